// Round 10
// baseline (1019.156 us; speedup 1.0000x reference)
//
#include <hip/hip_runtime.h>
#include <hip/hip_fp16.h>
#include <cstdint>

#define NCH 128
#define NGRAPHS 64
#define OUTC 10
#define POOL_CHUNK 256
#define NR 16      // dst/src ranges
#define BXS 32     // sub-blocks per range for bin/place
#define NBLK 512   // blocks for part/partition passes
#define RBMAX 6272 // max bins per range (N <= NR*RBMAX)

typedef __attribute__((ext_vector_type(8))) short s8v;
typedef __attribute__((ext_vector_type(8))) _Float16 h8v;
typedef __attribute__((ext_vector_type(4))) float f4v;

// ---------------- preprocessing: partition + counting sort, zero global atomics ----------------

__global__ __launch_bounds__(256) void part_count_kernel(const int* __restrict__ ei,
                                                         int* __restrict__ pc,
                                                         int* __restrict__ pcS,
                                                         int E, int RB) {
  __shared__ int cd[NR], cs[NR];
  int t = threadIdx.x, b = blockIdx.x;
  if (t < NR) { cd[t] = 0; cs[t] = 0; }
  __syncthreads();
  int chunk = (E + NBLK - 1) / NBLK;
  int i0 = b * chunk, i1 = min(i0 + chunk, E);
  for (int i = i0 + t; i < i1; i += 256) {
    atomicAdd(&cd[(unsigned)ei[E + i] / (unsigned)RB], 1);
    atomicAdd(&cs[(unsigned)ei[i] / (unsigned)RB], 1);
  }
  __syncthreads();
  if (t < NR) { pc[b * NR + t] = cd[t]; pcS[b * NR + t] = cs[t]; }
}

__global__ void offs_kernel(const int* __restrict__ pc, const int* __restrict__ pcS,
                            int* __restrict__ pairOff, int* __restrict__ srcOff,
                            int* __restrict__ gbase, int* __restrict__ sgbase, int E) {
  __shared__ int tot[NR], totS[NR];
  int t = threadIdx.x;
  if (t < NR) {
    int a = 0, as = 0;
    for (int b = 0; b < NBLK; ++b) { a += pc[b * NR + t]; as += pcS[b * NR + t]; }
    tot[t] = a; totS[t] = as;
  }
  __syncthreads();
  if (t == 0) {
    int acc = 0, accS = 0;
    for (int r = 0; r < NR; ++r) {
      gbase[r] = acc; acc += tot[r];
      sgbase[r] = accS; accS += totS[r];
    }
    gbase[NR] = E; sgbase[NR] = E;
  }
  __syncthreads();
  if (t < NR) {
    int acc = gbase[t], accS = sgbase[t];
    for (int b = 0; b < NBLK; ++b) {
      pairOff[b * NR + t] = acc; acc += pc[b * NR + t];
      srcOff[b * NR + t] = accS; accS += pcS[b * NR + t];
    }
  }
}

__global__ __launch_bounds__(256) void partition_kernel(const int* __restrict__ ei,
                                                        const int* __restrict__ pairOff,
                                                        const int* __restrict__ srcOff,
                                                        int* __restrict__ dsts,
                                                        int* __restrict__ srcs,
                                                        int* __restrict__ srcpart,
                                                        int E, int RB) {
  __shared__ int baseD[NR], baseS[NR], ctrD[NR], ctrS[NR];
  int t = threadIdx.x, b = blockIdx.x;
  if (t < NR) {
    baseD[t] = pairOff[b * NR + t]; ctrD[t] = 0;
    baseS[t] = srcOff[b * NR + t]; ctrS[t] = 0;
  }
  __syncthreads();
  int chunk = (E + NBLK - 1) / NBLK;
  int i0 = b * chunk, i1 = min(i0 + chunk, E);
  for (int i = i0 + t; i < i1; i += 256) {
    int d = ei[E + i], s = ei[i];
    int r = (unsigned)d / (unsigned)RB;
    int k = atomicAdd(&ctrD[r], 1);
    int pos = baseD[r] + k;
    dsts[pos] = d; srcs[pos] = s;
    int rs = (unsigned)s / (unsigned)RB;
    int k2 = atomicAdd(&ctrS[rs], 1);
    srcpart[baseS[rs] + k2] = s;
  }
}

__global__ __launch_bounds__(256) void binD_kernel(const int* __restrict__ dsts,
                                                   const int* __restrict__ gbase,
                                                   int* __restrict__ pbinsD, int RB) {
  __shared__ int bin[RBMAX];
  int t = threadIdx.x, x = blockIdx.x, y = blockIdx.y;
  for (int b = t; b < RB; b += 256) bin[b] = 0;
  __syncthreads();
  int segS = gbase[y], segE = gbase[y + 1];
  int chunk = (segE - segS + BXS - 1) / BXS;
  int i0 = segS + x * chunk, i1 = min(i0 + chunk, segE);
  int lo = y * RB;
  for (int i = i0 + t; i < i1; i += 256) atomicAdd(&bin[dsts[i] - lo], 1);
  __syncthreads();
  size_t base = (size_t)(y * BXS + x) * RB;
  for (int b = t; b < RB; b += 256) pbinsD[base + b] = bin[b];
}

__global__ __launch_bounds__(256) void binS_kernel(const int* __restrict__ srcpart,
                                                   const int* __restrict__ sgbase,
                                                   int* __restrict__ pbinsS, int RB) {
  __shared__ int bin[RBMAX];
  int t = threadIdx.x, x = blockIdx.x, y = blockIdx.y;
  for (int b = t; b < RB; b += 256) bin[b] = 0;
  __syncthreads();
  int segS = sgbase[y], segE = sgbase[y + 1];
  int chunk = (segE - segS + BXS - 1) / BXS;
  int i0 = segS + x * chunk, i1 = min(i0 + chunk, segE);
  int lo = y * RB;
  for (int i = i0 + t; i < i1; i += 256) atomicAdd(&bin[srcpart[i] - lo], 1);
  __syncthreads();
  size_t base = (size_t)(y * BXS + x) * RB;
  for (int b = t; b < RB; b += 256) pbinsS[base + b] = bin[b];
}

__global__ __launch_bounds__(256) void sc_dis_kernel(const int* __restrict__ pbinsS,
                                                     float* __restrict__ dis,
                                                     int N, int RB) {
  int n = blockIdx.x * 256 + threadIdx.x;
  if (n >= N) return;
  int y = n / RB, b = n - y * RB;
  int s = 0;
#pragma unroll
  for (int x = 0; x < BXS; ++x) s += pbinsS[(size_t)(y * BXS + x) * RB + b];
  dis[n] = s > 0 ? rsqrtf((float)s) : 0.0f;
}

__global__ __launch_bounds__(256) void range_scan_kernel(const int* __restrict__ pbinsD,
                                                         int* __restrict__ sbase, int RB) {
  __shared__ int wsum[4];
  __shared__ int carry_s;
  int t = threadIdx.x;
  int y = blockIdx.x;
  if (t == 0) carry_s = 0;
  __syncthreads();
  int nch = (RB + 255) / 256;
  for (int c = 0; c < nch; ++c) {
    int d = c * 256 + t;
    int v[BXS];
    int tv = 0;
#pragma unroll
    for (int x = 0; x < BXS; ++x) {
      v[x] = (d < RB) ? pbinsD[(size_t)(y * BXS + x) * RB + d] : 0;
      tv += v[x];
    }
    int lane = t & 63, w = t >> 6;
    int ps = tv;
    for (int dd = 1; dd < 64; dd <<= 1) {
      int o = __shfl_up(ps, dd);
      if (lane >= dd) ps += o;
    }
    if (lane == 63) wsum[w] = ps;
    __syncthreads();
    int woff = 0;
    for (int i = 0; i < w; ++i) woff += wsum[i];
    int ex = carry_s + woff + ps - tv;
    if (d < RB) {
      int run = ex;
#pragma unroll
      for (int x = 0; x < BXS; ++x) {
        sbase[(size_t)(y * BXS + x) * RB + d] = run;
        run += v[x];
      }
    }
    __syncthreads();
    if (t == 0) carry_s += wsum[0] + wsum[1] + wsum[2] + wsum[3];
    __syncthreads();
  }
}

__global__ __launch_bounds__(256) void rp_kernel(const int* __restrict__ sbase,
                                                 const int* __restrict__ gbase,
                                                 int* __restrict__ rp, int N, int RB, int E) {
  int n = blockIdx.x * 256 + threadIdx.x;
  if (n < N) {
    int y = n / RB, b = n - y * RB;
    rp[n] = gbase[y] + sbase[(size_t)(y * BXS) * RB + b];
  } else if (n == N) {
    rp[N] = E;
  }
}

__global__ __launch_bounds__(256) void place_kernel(const int* __restrict__ dsts,
                                                    const int* __restrict__ srcs,
                                                    const float* __restrict__ dis,
                                                    const int* __restrict__ sbase,
                                                    const int* __restrict__ gbase,
                                                    int2* __restrict__ sedge, int RB) {
  __shared__ int sb[RBMAX];
  int t = threadIdx.x, x = blockIdx.x, y = blockIdx.y;
  size_t pb = (size_t)(y * BXS + x) * RB;
  for (int b = t; b < RB; b += 256) sb[b] = sbase[pb + b];
  __syncthreads();
  int segS = gbase[y], segE = gbase[y + 1];
  int chunk = (segE - segS + BXS - 1) / BXS;
  int i0 = segS + x * chunk, i1 = min(i0 + chunk, segE);
  int lo = y * RB;
  int gb = gbase[y];
  for (int i = i0 + t; i < i1; i += 256) {
    int d = dsts[i], s = srcs[i];
    int pos = gb + atomicAdd(&sb[d - lo], 1);
    sedge[pos] = make_int2(s, __float_as_int(-dis[s] * dis[d]));
  }
}

__global__ __launch_bounds__(256) void f2h_kernel(const float* __restrict__ in,
                                                  __half* __restrict__ out, int n) {
  int i = (blockIdx.x * 256 + threadIdx.x) * 4;
  if (i + 3 < n) {
    float4 v = *(const float4*)&in[i];
    __half2 a = __float22half2_rn(make_float2(v.x, v.y));
    __half2 b = __float22half2_rn(make_float2(v.z, v.w));
    *(__half2*)&out[i] = a;
    *(__half2*)&out[i + 2] = b;
  } else {
    for (; i < n; ++i) out[i] = __float2half(in[i]);
  }
}

// --- weight prep: transpose + fp16 hi/lo(x2^11) split into MFMA-fragment-linear layout ---
__global__ __launch_bounds__(256) void prep_w_kernel(const float* __restrict__ W0,
                                                     const float* __restrict__ W1,
                                                     const float* __restrict__ W2,
                                                     __half* __restrict__ WFhi,
                                                     __half* __restrict__ WFlo) {
  int idx = blockIdx.x * 256 + threadIdx.x;
  const int TOT = 3 * 3 * 128 * 128;
  if (idx >= TOT) return;
  int j = idx & 7;
  int lane = (idx >> 3) & 63;
  int ct = (idx >> 9) & 7;
  int kwin = (idx >> 12) & 3;
  int p = (idx >> 14) % 3;
  int L = idx / (3 * 16384);
  int k = kwin * 32 + (lane >> 4) * 8 + j;
  int col = ct * 16 + (lane & 15);
  const float* W = (L == 0) ? W0 : ((L == 1) ? W1 : W2);
  float v = W[(p * 128 + k) * 128 + col];
  __half hi = __float2half_rn(v);
  float resid = v - __half2float(hi);
  __half lo = __float2half_rn(resid * 2048.0f);
  WFhi[idx] = hi;
  WFlo[idx] = lo;
}

// ---------------- propagate (fp16 operand): out[i] = sum_e norm_e * h[src_e] ----------------
__global__ __launch_bounds__(256) void prop_kernel(const __half* __restrict__ h,
                                                   __half* __restrict__ out,
                                                   const int* __restrict__ rp,
                                                   const int2* __restrict__ sedge, int N) {
  int node = blockIdx.x * 4 + (threadIdx.x >> 6);
  if (node >= N) return;
  int lane = threadIdx.x & 63;
  int half = lane >> 5;
  int c = (lane & 31) * 4;
  int e0 = rp[node], e1 = rp[node + 1];
  float a0 = 0.f, a1 = 0.f, a2 = 0.f, a3 = 0.f;
  int e = e0;
  for (; e + 8 <= e1; e += 8) {
#pragma unroll
    for (int u = 0; u < 4; ++u) {
      int2 Ed = sedge[e + 2 * u + half];
      float w = __int_as_float(Ed.y);
      uint2 raw = *(const uint2*)&h[(size_t)Ed.x * NCH + c];
      __half2 p = *(__half2*)&raw.x, q = *(__half2*)&raw.y;
      float2 f0 = __half22float2(p), f1 = __half22float2(q);
      a0 += w * f0.x; a1 += w * f0.y; a2 += w * f1.x; a3 += w * f1.y;
    }
  }
  if (e < e1) {
#pragma unroll
    for (int u = 0; u < 4; ++u) {
      int idx = e + 2 * u + half;
      if (idx < e1) {
        int2 Ed = sedge[idx];
        float w = __int_as_float(Ed.y);
        uint2 raw = *(const uint2*)&h[(size_t)Ed.x * NCH + c];
        __half2 p = *(__half2*)&raw.x, q = *(__half2*)&raw.y;
        float2 f0 = __half22float2(p), f1 = __half22float2(q);
        a0 += w * f0.x; a1 += w * f0.y; a2 += w * f1.x; a3 += w * f1.y;
      }
    }
  }
  a0 += __shfl_xor(a0, 32); a1 += __shfl_xor(a1, 32);
  a2 += __shfl_xor(a2, 32); a3 += __shfl_xor(a3, 32);
  if (half == 0) {
    __half2 r0 = __float22half2_rn(make_float2(a0, a1));
    __half2 r1 = __float22half2_rn(make_float2(a2, a3));
    uint2 st;
    st.x = *(unsigned*)&r0;
    st.y = *(unsigned*)&r1;
    *(uint2*)&out[(size_t)node * NCH + c] = st;
  }
}

// ------- fused Cheb GEMM, streaming A-fragments global->register, no LDS/barriers -------
// 1 wave per 64-thread block, 32 rows (2 row-tiles). A-frag for mfma_16x16x32_f16:
// row = lane&15, k = (lane>>4)*8+j => one 16B contiguous chunk of the activation row.
// out may alias h: each wave reads only its own rows, all reads precede its epilogue writes.
__global__ __launch_bounds__(64) void gemm_cheb_mfma(
    const __half* h, const __half* p1, const __half* p2,
    const __half* __restrict__ WFhi, const __half* __restrict__ WFlo,
    const float* __restrict__ bias, __half* out, int N, int relu) {
  int lane = threadIdx.x;
  int rowBase = blockIdx.x * 32;
  int r0 = min(rowBase + (lane & 15), N - 1);       // row-tile 0 (clamped; never stored OOB)
  int r1 = min(rowBase + 16 + (lane & 15), N - 1);  // row-tile 1
  int kb = (lane >> 4) * 8;

  f4v accH[2][8], accL[2][8];
#pragma unroll
  for (int rt = 0; rt < 2; ++rt)
#pragma unroll
    for (int ct = 0; ct < 8; ++ct) { accH[rt][ct] = (f4v)0.f; accL[rt][ct] = (f4v)0.f; }

#pragma unroll
  for (int phase = 0; phase < 3; ++phase) {
#pragma unroll
    for (int kwin = 0; kwin < 4; ++kwin) {
      int k = kwin * 32 + kb;
      h8v a0, a1;
      if (phase == 0) {
        a0 = *(const h8v*)&h[(size_t)r0 * NCH + k];
        a1 = *(const h8v*)&h[(size_t)r1 * NCH + k];
      } else if (phase == 1) {
        a0 = *(const h8v*)&p1[(size_t)r0 * NCH + k];
        a1 = *(const h8v*)&p1[(size_t)r1 * NCH + k];
      } else {
        union { h8v v; __half2 h2[4]; } u0, u1, v0, v1, o0, o1;
        u0.v = *(const h8v*)&p2[(size_t)r0 * NCH + k];
        u1.v = *(const h8v*)&p2[(size_t)r1 * NCH + k];
        v0.v = *(const h8v*)&h[(size_t)r0 * NCH + k];
        v1.v = *(const h8v*)&h[(size_t)r1 * NCH + k];
        const __half2 two = __floats2half2_rn(2.f, 2.f);
#pragma unroll
        for (int j = 0; j < 4; ++j) {
          o0.h2[j] = __hsub2(__hmul2(two, u0.h2[j]), v0.h2[j]);
          o1.h2[j] = __hsub2(__hmul2(two, u1.h2[j]), v1.h2[j]);
        }
        a0 = o0.v; a1 = o1.v;
      }
#pragma unroll
      for (int ct = 0; ct < 8; ++ct) {
        int boff = (phase * 4 + kwin) * 4096 + ct * 512 + lane * 8;
        h8v bh = *(const h8v*)&WFhi[boff];
        h8v bl = *(const h8v*)&WFlo[boff];
        accH[0][ct] = __builtin_amdgcn_mfma_f32_16x16x32_f16(a0, bh, accH[0][ct], 0, 0, 0);
        accH[1][ct] = __builtin_amdgcn_mfma_f32_16x16x32_f16(a1, bh, accH[1][ct], 0, 0, 0);
        accL[0][ct] = __builtin_amdgcn_mfma_f32_16x16x32_f16(a0, bl, accL[0][ct], 0, 0, 0);
        accL[1][ct] = __builtin_amdgcn_mfma_f32_16x16x32_f16(a1, bl, accL[1][ct], 0, 0, 0);
      }
    }
  }
  // epilogue: C/D layout col = lane&15, row = (lane>>4)*4 + reg
  int crow = (lane >> 4) * 4;
  int ccol = lane & 15;
  const float inv2048 = 1.0f / 2048.0f;
#pragma unroll
  for (int rt = 0; rt < 2; ++rt) {
    int gRow0 = rowBase + rt * 16 + crow;
#pragma unroll
    for (int reg = 0; reg < 4; ++reg) {
      int gRow = gRow0 + reg;
      if (gRow >= N) continue;
#pragma unroll
      for (int ct = 0; ct < 8; ++ct) {
        int col = ct * 16 + ccol;
        float vv = accH[rt][ct][reg] + accL[rt][ct][reg] * inv2048 + bias[col];
        if (relu) vv = fmaxf(vv, 0.f);
        out[(size_t)gRow * NCH + col] = __float2half(vv);
      }
    }
  }
}

// ---------------- pooling + final linear ----------------

__global__ __launch_bounds__(128) void pool_kernel(const __half* __restrict__ h,
                                                   const int* __restrict__ batch,
                                                   float* __restrict__ sums,
                                                   float* __restrict__ gcnt, int N) {
  int start = blockIdx.x * POOL_CHUNK;
  if (start >= N) return;
  int end = min(start + POOL_CHUNK, N);
  int c = threadIdx.x;
  float acc = 0.f;
  int cnt = 0;
  int cur = batch[start];
  for (int i = start; i < end; ++i) {
    int g = batch[i];
    if (g != cur) {
      atomicAdd(&sums[cur * NCH + c], acc);
      if (c == 0) atomicAdd(&gcnt[cur], (float)cnt);
      acc = 0.f; cnt = 0; cur = g;
    }
    acc += __half2float(h[(size_t)i * NCH + c]);
    ++cnt;
  }
  atomicAdd(&sums[cur * NCH + c], acc);
  if (c == 0) atomicAdd(&gcnt[cur], (float)cnt);
}

__global__ void final_kernel(const float* __restrict__ sums, const float* __restrict__ gcnt,
                             const float* __restrict__ lw, const float* __restrict__ lb,
                             float* __restrict__ out) {
  int g = blockIdx.x;
  int o = threadIdx.x;
  if (o >= OUTC) return;
  float inv = 1.0f / fmaxf(gcnt[g], 1.0f);
  float acc = lb[o];
  for (int ch = 0; ch < NCH; ++ch) acc += sums[g * NCH + ch] * inv * lw[ch * OUTC + o];
  out[g * OUTC + o] = acc;
}

// ---------------- launch ----------------

extern "C" void kernel_launch(void* const* d_in, const int* in_sizes, int n_in,
                              void* d_out, int out_size, void* d_ws, size_t ws_size,
                              hipStream_t stream) {
  const float* x  = (const float*)d_in[0];
  const int* ei   = (const int*)d_in[1];
  const int* batch= (const int*)d_in[2];
  const float* W0 = (const float*)d_in[3];
  const float* b0 = (const float*)d_in[4];
  const float* W1 = (const float*)d_in[5];
  const float* b1 = (const float*)d_in[6];
  const float* W2 = (const float*)d_in[7];
  const float* b2 = (const float*)d_in[8];
  const float* lw = (const float*)d_in[9];
  const float* lb = (const float*)d_in[10];
  float* out = (float*)d_out;
  int N = in_sizes[0] / NCH;
  int E = in_sizes[1] / 2;
  int RB = (N + NR - 1) / NR;  // bins per range (<= RBMAX)

  char* ws = (char*)d_ws;
  size_t off = 0;
  auto take = [&](size_t bytes) -> char* {
    char* p = ws + off;
    off += (bytes + 511) & ~(size_t)511;
    return p;
  };
  int* pc      = (int*)take((size_t)NBLK * NR * 4);
  int* pcS     = (int*)take((size_t)NBLK * NR * 4);
  int* pairOff = (int*)take((size_t)NBLK * NR * 4);
  int* srcOff  = (int*)take((size_t)NBLK * NR * 4);
  int* gbase   = (int*)take((NR + 1) * 4);
  int* sgbase  = (int*)take((NR + 1) * 4);
  int* dsts    = (int*)take((size_t)E * 4);
  int* srcs    = (int*)take((size_t)E * 4);
  int* srcpart = (int*)take((size_t)E * 4);
  int* pbinsD  = (int*)take((size_t)NR * BXS * RB * 4);
  int* pbinsS  = (int*)take((size_t)NR * BXS * RB * 4);
  int* sbase   = (int*)take((size_t)NR * BXS * RB * 4);
  float* dis   = (float*)take((size_t)N * 4);
  int* rp      = (int*)take((size_t)(N + 1) * 4);
  int2* sedge  = (int2*)take((size_t)E * 8);
  __half* x16  = (__half*)take((size_t)N * NCH * 2);
  __half* H16  = (__half*)take((size_t)N * NCH * 2);
  __half* P1h  = (__half*)take((size_t)N * NCH * 2);
  __half* P2h  = (__half*)take((size_t)N * NCH * 2);
  __half* WFhi = (__half*)take((size_t)3 * 3 * 128 * 128 * 2);
  __half* WFlo = (__half*)take((size_t)3 * 3 * 128 * 128 * 2);
  float* sums  = (float*)take((size_t)NGRAPHS * NCH * 4);
  float* gcnt  = (float*)take((size_t)NGRAPHS * 4);

  hipMemsetAsync(sums, 0, (size_t)NGRAPHS * NCH * 4, stream);
  hipMemsetAsync(gcnt, 0, (size_t)NGRAPHS * 4, stream);

  prep_w_kernel<<<(3 * 3 * 128 * 128 + 255) / 256, 256, 0, stream>>>(W0, W1, W2, WFhi, WFlo);
  f2h_kernel<<<(N * NCH / 4 + 255) / 256, 256, 0, stream>>>(x, x16, N * NCH);

  part_count_kernel<<<NBLK, 256, 0, stream>>>(ei, pc, pcS, E, RB);
  offs_kernel<<<1, 256, 0, stream>>>(pc, pcS, pairOff, srcOff, gbase, sgbase, E);
  partition_kernel<<<NBLK, 256, 0, stream>>>(ei, pairOff, srcOff, dsts, srcs, srcpart, E, RB);
  {
    dim3 g(BXS, NR, 1);
    binD_kernel<<<g, 256, 0, stream>>>(dsts, gbase, pbinsD, RB);
    binS_kernel<<<g, 256, 0, stream>>>(srcpart, sgbase, pbinsS, RB);
  }
  sc_dis_kernel<<<(N + 255) / 256, 256, 0, stream>>>(pbinsS, dis, N, RB);
  range_scan_kernel<<<NR, 256, 0, stream>>>(pbinsD, sbase, RB);
  rp_kernel<<<(N + 1 + 255) / 256, 256, 0, stream>>>(sbase, gbase, rp, N, RB, E);
  {
    dim3 g(BXS, NR, 1);
    place_kernel<<<g, 256, 0, stream>>>(dsts, srcs, dis, sbase, gbase, sedge, RB);
  }

  int pgrid = (N + 3) / 4;
  int ggrid = (N + 31) / 32;
  const int WL = 3 * 4 * 8 * 512;  // halfs per layer in WF layout

  // layer 0
  prop_kernel<<<pgrid, 256, 0, stream>>>(x16, P1h, rp, sedge, N);
  prop_kernel<<<pgrid, 256, 0, stream>>>(P1h, P2h, rp, sedge, N);
  gemm_cheb_mfma<<<ggrid, 64, 0, stream>>>(x16, P1h, P2h, WFhi + 0 * WL, WFlo + 0 * WL, b0, H16, N, 1);
  // layer 1 (out aliases h; safe: waves read only their own rows before writing them)
  prop_kernel<<<pgrid, 256, 0, stream>>>(H16, P1h, rp, sedge, N);
  prop_kernel<<<pgrid, 256, 0, stream>>>(P1h, P2h, rp, sedge, N);
  gemm_cheb_mfma<<<ggrid, 64, 0, stream>>>(H16, P1h, P2h, WFhi + 1 * WL, WFlo + 1 * WL, b1, H16, N, 1);
  // layer 2
  prop_kernel<<<pgrid, 256, 0, stream>>>(H16, P1h, rp, sedge, N);
  prop_kernel<<<pgrid, 256, 0, stream>>>(P1h, P2h, rp, sedge, N);
  gemm_cheb_mfma<<<ggrid, 64, 0, stream>>>(H16, P1h, P2h, WFhi + 2 * WL, WFlo + 2 * WL, b2, H16, N, 0);

  pool_kernel<<<(N + POOL_CHUNK - 1) / POOL_CHUNK, 128, 0, stream>>>(H16, batch, sums, gcnt, N);
  final_kernel<<<NGRAPHS, 16, 0, stream>>>(sums, gcnt, lw, lb, out);
}

// Round 11
// 915.226 us; speedup vs baseline: 1.1136x; 1.1136x over previous
//
#include <hip/hip_runtime.h>
#include <hip/hip_fp16.h>
#include <cstdint>

#define NCH 128
#define NGRAPHS 64
#define OUTC 10
#define POOL_CHUNK 256
#define NR 16      // dst/src ranges
#define BXS 32     // sub-blocks per range for bin/place
#define NBLK 512   // blocks for part/partition passes
#define RBMAX 6272 // max bins per range (N <= NR*RBMAX)

typedef __attribute__((ext_vector_type(8))) short s8v;
typedef __attribute__((ext_vector_type(8))) _Float16 h8v;
typedef __attribute__((ext_vector_type(4))) float f4v;

// ---------------- preprocessing: partition + counting sort, zero global atomics ----------------

__global__ __launch_bounds__(256) void part_count_kernel(const int* __restrict__ ei,
                                                         int* __restrict__ pc,
                                                         int* __restrict__ pcS,
                                                         int E, int RB) {
  __shared__ int cd[NR], cs[NR];
  int t = threadIdx.x, b = blockIdx.x;
  if (t < NR) { cd[t] = 0; cs[t] = 0; }
  __syncthreads();
  int chunk = (E + NBLK - 1) / NBLK;
  int i0 = b * chunk, i1 = min(i0 + chunk, E);
  for (int i = i0 + t; i < i1; i += 256) {
    atomicAdd(&cd[(unsigned)ei[E + i] / (unsigned)RB], 1);
    atomicAdd(&cs[(unsigned)ei[i] / (unsigned)RB], 1);
  }
  __syncthreads();
  if (t < NR) { pc[b * NR + t] = cd[t]; pcS[b * NR + t] = cs[t]; }
}

__global__ void offs_kernel(const int* __restrict__ pc, const int* __restrict__ pcS,
                            int* __restrict__ pairOff, int* __restrict__ srcOff,
                            int* __restrict__ gbase, int* __restrict__ sgbase, int E) {
  __shared__ int tot[NR], totS[NR];
  int t = threadIdx.x;
  if (t < NR) {
    int a = 0, as = 0;
    for (int b = 0; b < NBLK; ++b) { a += pc[b * NR + t]; as += pcS[b * NR + t]; }
    tot[t] = a; totS[t] = as;
  }
  __syncthreads();
  if (t == 0) {
    int acc = 0, accS = 0;
    for (int r = 0; r < NR; ++r) {
      gbase[r] = acc; acc += tot[r];
      sgbase[r] = accS; accS += totS[r];
    }
    gbase[NR] = E; sgbase[NR] = E;
  }
  __syncthreads();
  if (t < NR) {
    int acc = gbase[t], accS = sgbase[t];
    for (int b = 0; b < NBLK; ++b) {
      pairOff[b * NR + t] = acc; acc += pc[b * NR + t];
      srcOff[b * NR + t] = accS; accS += pcS[b * NR + t];
    }
  }
}

__global__ __launch_bounds__(256) void partition_kernel(const int* __restrict__ ei,
                                                        const int* __restrict__ pairOff,
                                                        const int* __restrict__ srcOff,
                                                        int* __restrict__ dsts,
                                                        int* __restrict__ srcs,
                                                        int* __restrict__ srcpart,
                                                        int E, int RB) {
  __shared__ int baseD[NR], baseS[NR], ctrD[NR], ctrS[NR];
  int t = threadIdx.x, b = blockIdx.x;
  if (t < NR) {
    baseD[t] = pairOff[b * NR + t]; ctrD[t] = 0;
    baseS[t] = srcOff[b * NR + t]; ctrS[t] = 0;
  }
  __syncthreads();
  int chunk = (E + NBLK - 1) / NBLK;
  int i0 = b * chunk, i1 = min(i0 + chunk, E);
  for (int i = i0 + t; i < i1; i += 256) {
    int d = ei[E + i], s = ei[i];
    int r = (unsigned)d / (unsigned)RB;
    int k = atomicAdd(&ctrD[r], 1);
    int pos = baseD[r] + k;
    dsts[pos] = d; srcs[pos] = s;
    int rs = (unsigned)s / (unsigned)RB;
    int k2 = atomicAdd(&ctrS[rs], 1);
    srcpart[baseS[rs] + k2] = s;
  }
}

__global__ __launch_bounds__(256) void binD_kernel(const int* __restrict__ dsts,
                                                   const int* __restrict__ gbase,
                                                   int* __restrict__ pbinsD, int RB) {
  __shared__ int bin[RBMAX];
  int t = threadIdx.x, x = blockIdx.x, y = blockIdx.y;
  for (int b = t; b < RB; b += 256) bin[b] = 0;
  __syncthreads();
  int segS = gbase[y], segE = gbase[y + 1];
  int chunk = (segE - segS + BXS - 1) / BXS;
  int i0 = segS + x * chunk, i1 = min(i0 + chunk, segE);
  int lo = y * RB;
  for (int i = i0 + t; i < i1; i += 256) atomicAdd(&bin[dsts[i] - lo], 1);
  __syncthreads();
  size_t base = (size_t)(y * BXS + x) * RB;
  for (int b = t; b < RB; b += 256) pbinsD[base + b] = bin[b];
}

__global__ __launch_bounds__(256) void binS_kernel(const int* __restrict__ srcpart,
                                                   const int* __restrict__ sgbase,
                                                   int* __restrict__ pbinsS, int RB) {
  __shared__ int bin[RBMAX];
  int t = threadIdx.x, x = blockIdx.x, y = blockIdx.y;
  for (int b = t; b < RB; b += 256) bin[b] = 0;
  __syncthreads();
  int segS = sgbase[y], segE = sgbase[y + 1];
  int chunk = (segE - segS + BXS - 1) / BXS;
  int i0 = segS + x * chunk, i1 = min(i0 + chunk, segE);
  int lo = y * RB;
  for (int i = i0 + t; i < i1; i += 256) atomicAdd(&bin[srcpart[i] - lo], 1);
  __syncthreads();
  size_t base = (size_t)(y * BXS + x) * RB;
  for (int b = t; b < RB; b += 256) pbinsS[base + b] = bin[b];
}

__global__ __launch_bounds__(256) void sc_dis_kernel(const int* __restrict__ pbinsS,
                                                     float* __restrict__ dis,
                                                     int N, int RB) {
  int n = blockIdx.x * 256 + threadIdx.x;
  if (n >= N) return;
  int y = n / RB, b = n - y * RB;
  int s = 0;
#pragma unroll
  for (int x = 0; x < BXS; ++x) s += pbinsS[(size_t)(y * BXS + x) * RB + b];
  dis[n] = s > 0 ? rsqrtf((float)s) : 0.0f;
}

__global__ __launch_bounds__(256) void range_scan_kernel(const int* __restrict__ pbinsD,
                                                         int* __restrict__ sbase, int RB) {
  __shared__ int wsum[4];
  __shared__ int carry_s;
  int t = threadIdx.x;
  int y = blockIdx.x;
  if (t == 0) carry_s = 0;
  __syncthreads();
  int nch = (RB + 255) / 256;
  for (int c = 0; c < nch; ++c) {
    int d = c * 256 + t;
    int v[BXS];
    int tv = 0;
#pragma unroll
    for (int x = 0; x < BXS; ++x) {
      v[x] = (d < RB) ? pbinsD[(size_t)(y * BXS + x) * RB + d] : 0;
      tv += v[x];
    }
    int lane = t & 63, w = t >> 6;
    int ps = tv;
    for (int dd = 1; dd < 64; dd <<= 1) {
      int o = __shfl_up(ps, dd);
      if (lane >= dd) ps += o;
    }
    if (lane == 63) wsum[w] = ps;
    __syncthreads();
    int woff = 0;
    for (int i = 0; i < w; ++i) woff += wsum[i];
    int ex = carry_s + woff + ps - tv;
    if (d < RB) {
      int run = ex;
#pragma unroll
      for (int x = 0; x < BXS; ++x) {
        sbase[(size_t)(y * BXS + x) * RB + d] = run;
        run += v[x];
      }
    }
    __syncthreads();
    if (t == 0) carry_s += wsum[0] + wsum[1] + wsum[2] + wsum[3];
    __syncthreads();
  }
}

__global__ __launch_bounds__(256) void rp_kernel(const int* __restrict__ sbase,
                                                 const int* __restrict__ gbase,
                                                 int* __restrict__ rp, int N, int RB, int E) {
  int n = blockIdx.x * 256 + threadIdx.x;
  if (n < N) {
    int y = n / RB, b = n - y * RB;
    rp[n] = gbase[y] + sbase[(size_t)(y * BXS) * RB + b];
  } else if (n == N) {
    rp[N] = E;
  }
}

__global__ __launch_bounds__(256) void place_kernel(const int* __restrict__ dsts,
                                                    const int* __restrict__ srcs,
                                                    const float* __restrict__ dis,
                                                    const int* __restrict__ sbase,
                                                    const int* __restrict__ gbase,
                                                    int2* __restrict__ sedge, int RB) {
  __shared__ int sb[RBMAX];
  int t = threadIdx.x, x = blockIdx.x, y = blockIdx.y;
  size_t pb = (size_t)(y * BXS + x) * RB;
  for (int b = t; b < RB; b += 256) sb[b] = sbase[pb + b];
  __syncthreads();
  int segS = gbase[y], segE = gbase[y + 1];
  int chunk = (segE - segS + BXS - 1) / BXS;
  int i0 = segS + x * chunk, i1 = min(i0 + chunk, segE);
  int lo = y * RB;
  int gb = gbase[y];
  for (int i = i0 + t; i < i1; i += 256) {
    int d = dsts[i], s = srcs[i];
    int pos = gb + atomicAdd(&sb[d - lo], 1);
    sedge[pos] = make_int2(s, __float_as_int(-dis[s] * dis[d]));
  }
}

__global__ __launch_bounds__(256) void f2h_kernel(const float* __restrict__ in,
                                                  __half* __restrict__ out, int n) {
  int i = (blockIdx.x * 256 + threadIdx.x) * 4;
  if (i + 3 < n) {
    float4 v = *(const float4*)&in[i];
    __half2 a = __float22half2_rn(make_float2(v.x, v.y));
    __half2 b = __float22half2_rn(make_float2(v.z, v.w));
    *(__half2*)&out[i] = a;
    *(__half2*)&out[i + 2] = b;
  } else {
    for (; i < n; ++i) out[i] = __float2half(in[i]);
  }
}

// --- weight prep: transpose + fp16 hi/lo(x2^11) split into MFMA-fragment-linear layout ---
__global__ __launch_bounds__(256) void prep_w_kernel(const float* __restrict__ W0,
                                                     const float* __restrict__ W1,
                                                     const float* __restrict__ W2,
                                                     __half* __restrict__ WFhi,
                                                     __half* __restrict__ WFlo) {
  int idx = blockIdx.x * 256 + threadIdx.x;
  const int TOT = 3 * 3 * 128 * 128;
  if (idx >= TOT) return;
  int j = idx & 7;
  int lane = (idx >> 3) & 63;
  int ct = (idx >> 9) & 7;
  int kwin = (idx >> 12) & 3;
  int p = (idx >> 14) % 3;
  int L = idx / (3 * 16384);
  int k = kwin * 32 + (lane >> 4) * 8 + j;
  int col = ct * 16 + (lane & 15);
  const float* W = (L == 0) ? W0 : ((L == 1) ? W1 : W2);
  float v = W[(p * 128 + k) * 128 + col];
  __half hi = __float2half_rn(v);
  float resid = v - __half2float(hi);
  __half lo = __float2half_rn(resid * 2048.0f);
  WFhi[idx] = hi;
  WFlo[idx] = lo;
}

// ---------------- propagate (fp16 operand): out[i] = sum_e norm_e * h[src_e] ----------------
__global__ __launch_bounds__(256) void prop_kernel(const __half* __restrict__ h,
                                                   __half* __restrict__ out,
                                                   const int* __restrict__ rp,
                                                   const int2* __restrict__ sedge, int N) {
  int node = blockIdx.x * 4 + (threadIdx.x >> 6);
  if (node >= N) return;
  int lane = threadIdx.x & 63;
  int half = lane >> 5;
  int c = (lane & 31) * 4;
  int e0 = rp[node], e1 = rp[node + 1];
  float a0 = 0.f, a1 = 0.f, a2 = 0.f, a3 = 0.f;
  int e = e0;
  for (; e + 8 <= e1; e += 8) {
#pragma unroll
    for (int u = 0; u < 4; ++u) {
      int2 Ed = sedge[e + 2 * u + half];
      float w = __int_as_float(Ed.y);
      uint2 raw = *(const uint2*)&h[(size_t)Ed.x * NCH + c];
      __half2 p = *(__half2*)&raw.x, q = *(__half2*)&raw.y;
      float2 f0 = __half22float2(p), f1 = __half22float2(q);
      a0 += w * f0.x; a1 += w * f0.y; a2 += w * f1.x; a3 += w * f1.y;
    }
  }
  if (e < e1) {
#pragma unroll
    for (int u = 0; u < 4; ++u) {
      int idx = e + 2 * u + half;
      if (idx < e1) {
        int2 Ed = sedge[idx];
        float w = __int_as_float(Ed.y);
        uint2 raw = *(const uint2*)&h[(size_t)Ed.x * NCH + c];
        __half2 p = *(__half2*)&raw.x, q = *(__half2*)&raw.y;
        float2 f0 = __half22float2(p), f1 = __half22float2(q);
        a0 += w * f0.x; a1 += w * f0.y; a2 += w * f1.x; a3 += w * f1.y;
      }
    }
  }
  a0 += __shfl_xor(a0, 32); a1 += __shfl_xor(a1, 32);
  a2 += __shfl_xor(a2, 32); a3 += __shfl_xor(a3, 32);
  if (half == 0) {
    __half2 r0 = __float22half2_rn(make_float2(a0, a1));
    __half2 r1 = __float22half2_rn(make_float2(a2, a3));
    uint2 st;
    st.x = *(unsigned*)&r0;
    st.y = *(unsigned*)&r1;
    *(uint2*)&out[(size_t)node * NCH + c] = st;
  }
}

// ------- fused Cheb GEMM, A-fragments global->register, no LDS; 4 waves/block -------
// Each wave owns ONE 16-row tile (block = 64 rows). A-frag for mfma_16x16x32_f16 is a
// contiguous 16B chunk: row = lane&15, k = (lane>>4)*8+j. Dual fp32 accumulators for
// W = Whi + Wlo/2048. out may alias h: a wave reads only its own rows, and all its
// reads precede its epilogue writes.
__global__ __launch_bounds__(256) void gemm_cheb_mfma(
    const __half* h, const __half* p1, const __half* p2,
    const __half* __restrict__ WFhi, const __half* __restrict__ WFlo,
    const float* __restrict__ bias, __half* out, int N, int relu) {
  int t = threadIdx.x;
  int w = t >> 6, lane = t & 63;
  int rowBase = blockIdx.x * 64 + w * 16;
  int r0 = min(rowBase + (lane & 15), N - 1);  // clamped; OOB rows never stored
  int kb = (lane >> 4) * 8;

  f4v accH[8], accL[8];
#pragma unroll
  for (int ct = 0; ct < 8; ++ct) { accH[ct] = (f4v)0.f; accL[ct] = (f4v)0.f; }

  for (int phase = 0; phase < 3; ++phase) {
#pragma unroll
    for (int kwin = 0; kwin < 4; ++kwin) {
      int k = kwin * 32 + kb;
      h8v a0;
      if (phase == 0) {
        a0 = *(const h8v*)&h[(size_t)r0 * NCH + k];
      } else if (phase == 1) {
        a0 = *(const h8v*)&p1[(size_t)r0 * NCH + k];
      } else {
        union { h8v v; __half2 h2[4]; } u0, v0, o0;
        u0.v = *(const h8v*)&p2[(size_t)r0 * NCH + k];
        v0.v = *(const h8v*)&h[(size_t)r0 * NCH + k];
        const __half2 two = __floats2half2_rn(2.f, 2.f);
#pragma unroll
        for (int j = 0; j < 4; ++j) o0.h2[j] = __hsub2(__hmul2(two, u0.h2[j]), v0.h2[j]);
        a0 = o0.v;
      }
#pragma unroll
      for (int ct = 0; ct < 8; ++ct) {
        int boff = (phase * 4 + kwin) * 4096 + ct * 512 + lane * 8;
        h8v bh = *(const h8v*)&WFhi[boff];
        h8v bl = *(const h8v*)&WFlo[boff];
        accH[ct] = __builtin_amdgcn_mfma_f32_16x16x32_f16(a0, bh, accH[ct], 0, 0, 0);
        accL[ct] = __builtin_amdgcn_mfma_f32_16x16x32_f16(a0, bl, accL[ct], 0, 0, 0);
      }
    }
  }
  // epilogue: C/D layout col = lane&15, row = (lane>>4)*4 + reg
  int crow = (lane >> 4) * 4;
  int ccol = lane & 15;
  const float inv2048 = 1.0f / 2048.0f;
#pragma unroll
  for (int reg = 0; reg < 4; ++reg) {
    int gRow = rowBase + crow + reg;
    if (gRow >= N) continue;
#pragma unroll
    for (int ct = 0; ct < 8; ++ct) {
      int col = ct * 16 + ccol;
      float vv = accH[ct][reg] + accL[ct][reg] * inv2048 + bias[col];
      if (relu) vv = fmaxf(vv, 0.f);
      out[(size_t)gRow * NCH + col] = __float2half(vv);
    }
  }
}

// ---------------- pooling + final linear ----------------

__global__ __launch_bounds__(128) void pool_kernel(const __half* __restrict__ h,
                                                   const int* __restrict__ batch,
                                                   float* __restrict__ sums,
                                                   float* __restrict__ gcnt, int N) {
  int start = blockIdx.x * POOL_CHUNK;
  if (start >= N) return;
  int end = min(start + POOL_CHUNK, N);
  int c = threadIdx.x;
  float acc = 0.f;
  int cnt = 0;
  int cur = batch[start];
  for (int i = start; i < end; ++i) {
    int g = batch[i];
    if (g != cur) {
      atomicAdd(&sums[cur * NCH + c], acc);
      if (c == 0) atomicAdd(&gcnt[cur], (float)cnt);
      acc = 0.f; cnt = 0; cur = g;
    }
    acc += __half2float(h[(size_t)i * NCH + c]);
    ++cnt;
  }
  atomicAdd(&sums[cur * NCH + c], acc);
  if (c == 0) atomicAdd(&gcnt[cur], (float)cnt);
}

__global__ void final_kernel(const float* __restrict__ sums, const float* __restrict__ gcnt,
                             const float* __restrict__ lw, const float* __restrict__ lb,
                             float* __restrict__ out) {
  int g = blockIdx.x;
  int o = threadIdx.x;
  if (o >= OUTC) return;
  float inv = 1.0f / fmaxf(gcnt[g], 1.0f);
  float acc = lb[o];
  for (int ch = 0; ch < NCH; ++ch) acc += sums[g * NCH + ch] * inv * lw[ch * OUTC + o];
  out[g * OUTC + o] = acc;
}

// ---------------- launch ----------------

extern "C" void kernel_launch(void* const* d_in, const int* in_sizes, int n_in,
                              void* d_out, int out_size, void* d_ws, size_t ws_size,
                              hipStream_t stream) {
  const float* x  = (const float*)d_in[0];
  const int* ei   = (const int*)d_in[1];
  const int* batch= (const int*)d_in[2];
  const float* W0 = (const float*)d_in[3];
  const float* b0 = (const float*)d_in[4];
  const float* W1 = (const float*)d_in[5];
  const float* b1 = (const float*)d_in[6];
  const float* W2 = (const float*)d_in[7];
  const float* b2 = (const float*)d_in[8];
  const float* lw = (const float*)d_in[9];
  const float* lb = (const float*)d_in[10];
  float* out = (float*)d_out;
  int N = in_sizes[0] / NCH;
  int E = in_sizes[1] / 2;
  int RB = (N + NR - 1) / NR;  // bins per range (<= RBMAX)

  char* ws = (char*)d_ws;
  size_t off = 0;
  auto take = [&](size_t bytes) -> char* {
    char* p = ws + off;
    off += (bytes + 511) & ~(size_t)511;
    return p;
  };
  int* pc      = (int*)take((size_t)NBLK * NR * 4);
  int* pcS     = (int*)take((size_t)NBLK * NR * 4);
  int* pairOff = (int*)take((size_t)NBLK * NR * 4);
  int* srcOff  = (int*)take((size_t)NBLK * NR * 4);
  int* gbase   = (int*)take((NR + 1) * 4);
  int* sgbase  = (int*)take((NR + 1) * 4);
  int* dsts    = (int*)take((size_t)E * 4);
  int* srcs    = (int*)take((size_t)E * 4);
  int* srcpart = (int*)take((size_t)E * 4);
  int* pbinsD  = (int*)take((size_t)NR * BXS * RB * 4);
  int* pbinsS  = (int*)take((size_t)NR * BXS * RB * 4);
  int* sbase   = (int*)take((size_t)NR * BXS * RB * 4);
  float* dis   = (float*)take((size_t)N * 4);
  int* rp      = (int*)take((size_t)(N + 1) * 4);
  int2* sedge  = (int2*)take((size_t)E * 8);
  __half* x16  = (__half*)take((size_t)N * NCH * 2);
  __half* H16  = (__half*)take((size_t)N * NCH * 2);
  __half* P1h  = (__half*)take((size_t)N * NCH * 2);
  __half* P2h  = (__half*)take((size_t)N * NCH * 2);
  __half* WFhi = (__half*)take((size_t)3 * 3 * 128 * 128 * 2);
  __half* WFlo = (__half*)take((size_t)3 * 3 * 128 * 128 * 2);
  float* sums  = (float*)take((size_t)NGRAPHS * NCH * 4);
  float* gcnt  = (float*)take((size_t)NGRAPHS * 4);

  hipMemsetAsync(sums, 0, (size_t)NGRAPHS * NCH * 4, stream);
  hipMemsetAsync(gcnt, 0, (size_t)NGRAPHS * 4, stream);

  prep_w_kernel<<<(3 * 3 * 128 * 128 + 255) / 256, 256, 0, stream>>>(W0, W1, W2, WFhi, WFlo);
  f2h_kernel<<<(N * NCH / 4 + 255) / 256, 256, 0, stream>>>(x, x16, N * NCH);

  part_count_kernel<<<NBLK, 256, 0, stream>>>(ei, pc, pcS, E, RB);
  offs_kernel<<<1, 256, 0, stream>>>(pc, pcS, pairOff, srcOff, gbase, sgbase, E);
  partition_kernel<<<NBLK, 256, 0, stream>>>(ei, pairOff, srcOff, dsts, srcs, srcpart, E, RB);
  {
    dim3 g(BXS, NR, 1);
    binD_kernel<<<g, 256, 0, stream>>>(dsts, gbase, pbinsD, RB);
    binS_kernel<<<g, 256, 0, stream>>>(srcpart, sgbase, pbinsS, RB);
  }
  sc_dis_kernel<<<(N + 255) / 256, 256, 0, stream>>>(pbinsS, dis, N, RB);
  range_scan_kernel<<<NR, 256, 0, stream>>>(pbinsD, sbase, RB);
  rp_kernel<<<(N + 1 + 255) / 256, 256, 0, stream>>>(sbase, gbase, rp, N, RB, E);
  {
    dim3 g(BXS, NR, 1);
    place_kernel<<<g, 256, 0, stream>>>(dsts, srcs, dis, sbase, gbase, sedge, RB);
  }

  int pgrid = (N + 3) / 4;
  int ggrid = (N + 63) / 64;
  const int WL = 3 * 4 * 8 * 512;  // halfs per layer in WF layout

  // layer 0
  prop_kernel<<<pgrid, 256, 0, stream>>>(x16, P1h, rp, sedge, N);
  prop_kernel<<<pgrid, 256, 0, stream>>>(P1h, P2h, rp, sedge, N);
  gemm_cheb_mfma<<<ggrid, 256, 0, stream>>>(x16, P1h, P2h, WFhi + 0 * WL, WFlo + 0 * WL, b0, H16, N, 1);
  // layer 1 (out aliases h; safe: waves read only their own rows before writing them)
  prop_kernel<<<pgrid, 256, 0, stream>>>(H16, P1h, rp, sedge, N);
  prop_kernel<<<pgrid, 256, 0, stream>>>(P1h, P2h, rp, sedge, N);
  gemm_cheb_mfma<<<ggrid, 256, 0, stream>>>(H16, P1h, P2h, WFhi + 1 * WL, WFlo + 1 * WL, b1, H16, N, 1);
  // layer 2
  prop_kernel<<<pgrid, 256, 0, stream>>>(H16, P1h, rp, sedge, N);
  prop_kernel<<<pgrid, 256, 0, stream>>>(P1h, P2h, rp, sedge, N);
  gemm_cheb_mfma<<<ggrid, 256, 0, stream>>>(H16, P1h, P2h, WFhi + 2 * WL, WFlo + 2 * WL, b2, H16, N, 0);

  pool_kernel<<<(N + POOL_CHUNK - 1) / POOL_CHUNK, 128, 0, stream>>>(H16, batch, sums, gcnt, N);
  final_kernel<<<NGRAPHS, 16, 0, stream>>>(sums, gcnt, lw, lb, out);
}

// Round 12
// 721.006 us; speedup vs baseline: 1.4135x; 1.2694x over previous
//
#include <hip/hip_runtime.h>
#include <hip/hip_fp16.h>
#include <cstdint>

#define NCH 128
#define NGRAPHS 64
#define OUTC 10
#define POOL_CHUNK 256
#define NR 16      // dst/src ranges
#define BXS 32     // sub-blocks per range for bin/place
#define NBLK 512   // blocks for part/partition passes
#define RBMAX 6272 // max bins per range (N <= NR*RBMAX)

typedef __attribute__((ext_vector_type(8))) short s8v;
typedef __attribute__((ext_vector_type(8))) _Float16 h8v;
typedef __attribute__((ext_vector_type(4))) float f4v;

// ---------------- preprocessing: partition + counting sort, zero global atomics ----------------

__global__ __launch_bounds__(256) void part_count_kernel(const int* __restrict__ ei,
                                                         int* __restrict__ pc,
                                                         int* __restrict__ pcS,
                                                         int E, int RB) {
  __shared__ int cd[NR], cs[NR];
  int t = threadIdx.x, b = blockIdx.x;
  if (t < NR) { cd[t] = 0; cs[t] = 0; }
  __syncthreads();
  int chunk = (E + NBLK - 1) / NBLK;
  int i0 = b * chunk, i1 = min(i0 + chunk, E);
  for (int i = i0 + t; i < i1; i += 256) {
    atomicAdd(&cd[(unsigned)ei[E + i] / (unsigned)RB], 1);
    atomicAdd(&cs[(unsigned)ei[i] / (unsigned)RB], 1);
  }
  __syncthreads();
  if (t < NR) { pc[b * NR + t] = cd[t]; pcS[b * NR + t] = cs[t]; }
}

__global__ void offs_kernel(const int* __restrict__ pc, const int* __restrict__ pcS,
                            int* __restrict__ pairOff, int* __restrict__ srcOff,
                            int* __restrict__ gbase, int* __restrict__ sgbase, int E) {
  __shared__ int tot[NR], totS[NR];
  int t = threadIdx.x;
  if (t < NR) {
    int a = 0, as = 0;
    for (int b = 0; b < NBLK; ++b) { a += pc[b * NR + t]; as += pcS[b * NR + t]; }
    tot[t] = a; totS[t] = as;
  }
  __syncthreads();
  if (t == 0) {
    int acc = 0, accS = 0;
    for (int r = 0; r < NR; ++r) {
      gbase[r] = acc; acc += tot[r];
      sgbase[r] = accS; accS += totS[r];
    }
    gbase[NR] = E; sgbase[NR] = E;
  }
  __syncthreads();
  if (t < NR) {
    int acc = gbase[t], accS = sgbase[t];
    for (int b = 0; b < NBLK; ++b) {
      pairOff[b * NR + t] = acc; acc += pc[b * NR + t];
      srcOff[b * NR + t] = accS; accS += pcS[b * NR + t];
    }
  }
}

__global__ __launch_bounds__(256) void partition_kernel(const int* __restrict__ ei,
                                                        const int* __restrict__ pairOff,
                                                        const int* __restrict__ srcOff,
                                                        int* __restrict__ dsts,
                                                        int* __restrict__ srcs,
                                                        int* __restrict__ srcpart,
                                                        int E, int RB) {
  __shared__ int baseD[NR], baseS[NR], ctrD[NR], ctrS[NR];
  int t = threadIdx.x, b = blockIdx.x;
  if (t < NR) {
    baseD[t] = pairOff[b * NR + t]; ctrD[t] = 0;
    baseS[t] = srcOff[b * NR + t]; ctrS[t] = 0;
  }
  __syncthreads();
  int chunk = (E + NBLK - 1) / NBLK;
  int i0 = b * chunk, i1 = min(i0 + chunk, E);
  for (int i = i0 + t; i < i1; i += 256) {
    int d = ei[E + i], s = ei[i];
    int r = (unsigned)d / (unsigned)RB;
    int k = atomicAdd(&ctrD[r], 1);
    int pos = baseD[r] + k;
    dsts[pos] = d; srcs[pos] = s;
    int rs = (unsigned)s / (unsigned)RB;
    int k2 = atomicAdd(&ctrS[rs], 1);
    srcpart[baseS[rs] + k2] = s;
  }
}

__global__ __launch_bounds__(256) void binD_kernel(const int* __restrict__ dsts,
                                                   const int* __restrict__ gbase,
                                                   int* __restrict__ pbinsD, int RB) {
  __shared__ int bin[RBMAX];
  int t = threadIdx.x, x = blockIdx.x, y = blockIdx.y;
  for (int b = t; b < RB; b += 256) bin[b] = 0;
  __syncthreads();
  int segS = gbase[y], segE = gbase[y + 1];
  int chunk = (segE - segS + BXS - 1) / BXS;
  int i0 = segS + x * chunk, i1 = min(i0 + chunk, segE);
  int lo = y * RB;
  for (int i = i0 + t; i < i1; i += 256) atomicAdd(&bin[dsts[i] - lo], 1);
  __syncthreads();
  size_t base = (size_t)(y * BXS + x) * RB;
  for (int b = t; b < RB; b += 256) pbinsD[base + b] = bin[b];
}

__global__ __launch_bounds__(256) void binS_kernel(const int* __restrict__ srcpart,
                                                   const int* __restrict__ sgbase,
                                                   int* __restrict__ pbinsS, int RB) {
  __shared__ int bin[RBMAX];
  int t = threadIdx.x, x = blockIdx.x, y = blockIdx.y;
  for (int b = t; b < RB; b += 256) bin[b] = 0;
  __syncthreads();
  int segS = sgbase[y], segE = sgbase[y + 1];
  int chunk = (segE - segS + BXS - 1) / BXS;
  int i0 = segS + x * chunk, i1 = min(i0 + chunk, segE);
  int lo = y * RB;
  for (int i = i0 + t; i < i1; i += 256) atomicAdd(&bin[srcpart[i] - lo], 1);
  __syncthreads();
  size_t base = (size_t)(y * BXS + x) * RB;
  for (int b = t; b < RB; b += 256) pbinsS[base + b] = bin[b];
}

__global__ __launch_bounds__(256) void sc_dis_kernel(const int* __restrict__ pbinsS,
                                                     float* __restrict__ dis,
                                                     int N, int RB) {
  int n = blockIdx.x * 256 + threadIdx.x;
  if (n >= N) return;
  int y = n / RB, b = n - y * RB;
  int s = 0;
#pragma unroll
  for (int x = 0; x < BXS; ++x) s += pbinsS[(size_t)(y * BXS + x) * RB + b];
  dis[n] = s > 0 ? rsqrtf((float)s) : 0.0f;
}

__global__ __launch_bounds__(256) void range_scan_kernel(const int* __restrict__ pbinsD,
                                                         int* __restrict__ sbase, int RB) {
  __shared__ int wsum[4];
  __shared__ int carry_s;
  int t = threadIdx.x;
  int y = blockIdx.x;
  if (t == 0) carry_s = 0;
  __syncthreads();
  int nch = (RB + 255) / 256;
  for (int c = 0; c < nch; ++c) {
    int d = c * 256 + t;
    int v[BXS];
    int tv = 0;
#pragma unroll
    for (int x = 0; x < BXS; ++x) {
      v[x] = (d < RB) ? pbinsD[(size_t)(y * BXS + x) * RB + d] : 0;
      tv += v[x];
    }
    int lane = t & 63, w = t >> 6;
    int ps = tv;
    for (int dd = 1; dd < 64; dd <<= 1) {
      int o = __shfl_up(ps, dd);
      if (lane >= dd) ps += o;
    }
    if (lane == 63) wsum[w] = ps;
    __syncthreads();
    int woff = 0;
    for (int i = 0; i < w; ++i) woff += wsum[i];
    int ex = carry_s + woff + ps - tv;
    if (d < RB) {
      int run = ex;
#pragma unroll
      for (int x = 0; x < BXS; ++x) {
        sbase[(size_t)(y * BXS + x) * RB + d] = run;
        run += v[x];
      }
    }
    __syncthreads();
    if (t == 0) carry_s += wsum[0] + wsum[1] + wsum[2] + wsum[3];
    __syncthreads();
  }
}

__global__ __launch_bounds__(256) void rp_kernel(const int* __restrict__ sbase,
                                                 const int* __restrict__ gbase,
                                                 int* __restrict__ rp, int N, int RB, int E) {
  int n = blockIdx.x * 256 + threadIdx.x;
  if (n < N) {
    int y = n / RB, b = n - y * RB;
    rp[n] = gbase[y] + sbase[(size_t)(y * BXS) * RB + b];
  } else if (n == N) {
    rp[N] = E;
  }
}

__global__ __launch_bounds__(256) void place_kernel(const int* __restrict__ dsts,
                                                    const int* __restrict__ srcs,
                                                    const float* __restrict__ dis,
                                                    const int* __restrict__ sbase,
                                                    const int* __restrict__ gbase,
                                                    int2* __restrict__ sedge, int RB) {
  __shared__ int sb[RBMAX];
  int t = threadIdx.x, x = blockIdx.x, y = blockIdx.y;
  size_t pb = (size_t)(y * BXS + x) * RB;
  for (int b = t; b < RB; b += 256) sb[b] = sbase[pb + b];
  __syncthreads();
  int segS = gbase[y], segE = gbase[y + 1];
  int chunk = (segE - segS + BXS - 1) / BXS;
  int i0 = segS + x * chunk, i1 = min(i0 + chunk, segE);
  int lo = y * RB;
  int gb = gbase[y];
  for (int i = i0 + t; i < i1; i += 256) {
    int d = dsts[i], s = srcs[i];
    int pos = gb + atomicAdd(&sb[d - lo], 1);
    sedge[pos] = make_int2(s, __float_as_int(-dis[s] * dis[d]));
  }
}

__global__ __launch_bounds__(256) void f2h_kernel(const float* __restrict__ in,
                                                  __half* __restrict__ out, int n) {
  int i = (blockIdx.x * 256 + threadIdx.x) * 4;
  if (i + 3 < n) {
    float4 v = *(const float4*)&in[i];
    __half2 a = __float22half2_rn(make_float2(v.x, v.y));
    __half2 b = __float22half2_rn(make_float2(v.z, v.w));
    *(__half2*)&out[i] = a;
    *(__half2*)&out[i + 2] = b;
  } else {
    for (; i < n; ++i) out[i] = __float2half(in[i]);
  }
}

// --- weight prep: PRECOMBINED phases (W0-W2, W1, 2*W2) + fp16 hi/lo(x2^11) split,
// MFMA-fragment-linear layout: per layer L, phase p: [kwin][ct][lane][8];
// element = Wp[k][col], k = kwin*32 + (lane>>4)*8 + j, col = ct*16 + (lane&15)
__global__ __launch_bounds__(256) void prep_w_kernel(const float* __restrict__ W0,
                                                     const float* __restrict__ W1,
                                                     const float* __restrict__ W2,
                                                     __half* __restrict__ WFhi,
                                                     __half* __restrict__ WFlo) {
  int idx = blockIdx.x * 256 + threadIdx.x;
  const int TOT = 3 * 3 * 128 * 128;
  if (idx >= TOT) return;
  int j = idx & 7;
  int lane = (idx >> 3) & 63;
  int ct = (idx >> 9) & 7;
  int kwin = (idx >> 12) & 3;
  int p = (idx >> 14) % 3;
  int L = idx / (3 * 16384);
  int k = kwin * 32 + (lane >> 4) * 8 + j;
  int col = ct * 16 + (lane & 15);
  const float* W = (L == 0) ? W0 : ((L == 1) ? W1 : W2);
  float v;
  if (p == 0)      v = W[(0 * 128 + k) * 128 + col] - W[(2 * 128 + k) * 128 + col];
  else if (p == 1) v = W[(1 * 128 + k) * 128 + col];
  else             v = 2.0f * W[(2 * 128 + k) * 128 + col];
  __half hi = __float2half_rn(v);
  float resid = v - __half2float(hi);
  __half lo = __float2half_rn(resid * 2048.0f);
  WFhi[idx] = hi;
  WFlo[idx] = lo;
}

// ---------------- propagate (fp16): out[i] = sum_e norm_e * h[src_e] ----------------
// 16 lanes per edge (16B/lane): one load instruction fetches FOUR 256B rows.
__device__ __forceinline__ void fma8(float* a, float w, uint4 raw) {
  __half2* ph = (__half2*)&raw;
#pragma unroll
  for (int j = 0; j < 4; ++j) {
    float2 f = __half22float2(ph[j]);
    a[2 * j] += w * f.x;
    a[2 * j + 1] += w * f.y;
  }
}

__global__ __launch_bounds__(256) void prop_kernel(const __half* __restrict__ h,
                                                   __half* __restrict__ out,
                                                   const int* __restrict__ rp,
                                                   const int2* __restrict__ sedge, int N) {
  int node = blockIdx.x * 4 + (threadIdx.x >> 6);
  if (node >= N) return;
  int lane = threadIdx.x & 63;
  int q = lane >> 4;           // quarter owns edge e+q
  int c = (lane & 15) * 8;     // 8 halves = 16B per lane
  int e0 = rp[node], e1 = rp[node + 1];
  float a[8];
#pragma unroll
  for (int j = 0; j < 8; ++j) a[j] = 0.f;
  int e = e0;
  for (; e + 8 <= e1; e += 8) {  // 8 edges in flight (2 loads/lane)
    int2 E0 = sedge[e + q];
    int2 E1 = sedge[e + 4 + q];
    uint4 r0 = *(const uint4*)&h[(size_t)E0.x * NCH + c];
    uint4 r1 = *(const uint4*)&h[(size_t)E1.x * NCH + c];
    fma8(a, __int_as_float(E0.y), r0);
    fma8(a, __int_as_float(E1.y), r1);
  }
  for (; e + 4 <= e1; e += 4) {
    int2 E0 = sedge[e + q];
    uint4 r0 = *(const uint4*)&h[(size_t)E0.x * NCH + c];
    fma8(a, __int_as_float(E0.y), r0);
  }
  if (e < e1) {
    int idx = e + q;
    if (idx < e1) {
      int2 E0 = sedge[idx];
      uint4 r0 = *(const uint4*)&h[(size_t)E0.x * NCH + c];
      fma8(a, __int_as_float(E0.y), r0);
    }
  }
#pragma unroll
  for (int j = 0; j < 8; ++j) {
    a[j] += __shfl_xor(a[j], 16);
    a[j] += __shfl_xor(a[j], 32);
  }
  if (q == 0) {
    uint4 st;
    __half2* ph = (__half2*)&st;
#pragma unroll
    for (int j = 0; j < 4; ++j)
      ph[j] = __float22half2_rn(make_float2(a[2 * j], a[2 * j + 1]));
    *(uint4*)&out[(size_t)node * NCH + c] = st;
  }
}

// ------- fused Cheb GEMM v3: B staged through LDS, A global->reg, precombined W -------
// out = h@(W0-W2) + p1@W1 + p2@(2*W2) + b. 4 waves/block, 1 row-tile (16 rows) per wave.
// Per step s = (phase,kwin): 256 threads cooperatively stage the 8KB+8KB B-chunk into
// LDS (independent coalesced loads), then each wave does 16 ds_read_b128 + 16 MFMA.
// out may alias h: a wave reads only its own rows; reads precede its epilogue writes.
__global__ __launch_bounds__(256) void gemm_cheb_mfma(
    const __half* h, const __half* p1, const __half* p2,
    const __half* __restrict__ WFhi, const __half* __restrict__ WFlo,
    const float* __restrict__ bias, __half* out, int N, int relu) {
  __shared__ __align__(16) __half Bh[4096];
  __shared__ __align__(16) __half Bl[4096];
  int t = threadIdx.x;
  int w = t >> 6, lane = t & 63;
  int rowBase = blockIdx.x * 64 + w * 16;
  int r0 = min(rowBase + (lane & 15), N - 1);  // clamped; OOB rows never stored
  int kb = (lane >> 4) * 8;

  f4v accH[8], accL[8];
#pragma unroll
  for (int ct = 0; ct < 8; ++ct) { accH[ct] = (f4v)0.f; accL[ct] = (f4v)0.f; }

  for (int s = 0; s < 12; ++s) {
    int phase = s >> 2, kwin = s & 3;
    // issue B-stage global loads early (latency overlaps prev compute + barrier)
    const __half* bsrcH = WFhi + s * 4096;
    const __half* bsrcL = WFlo + s * 4096;
    s8v g0 = *(const s8v*)&bsrcH[t * 8];
    s8v g1 = *(const s8v*)&bsrcH[2048 + t * 8];
    s8v g2 = *(const s8v*)&bsrcL[t * 8];
    s8v g3 = *(const s8v*)&bsrcL[2048 + t * 8];
    // A fragment: contiguous 16B chunk, row=lane&15, k=(lane>>4)*8+j
    int k = kwin * 32 + kb;
    h8v a0;
    if (phase == 0)      a0 = *(const h8v*)&h [(size_t)r0 * NCH + k];
    else if (phase == 1) a0 = *(const h8v*)&p1[(size_t)r0 * NCH + k];
    else                 a0 = *(const h8v*)&p2[(size_t)r0 * NCH + k];
    if (s) __syncthreads();  // previous step's LDS reads complete before overwrite
    *(s8v*)&Bh[t * 8] = g0;
    *(s8v*)&Bh[2048 + t * 8] = g1;
    *(s8v*)&Bl[t * 8] = g2;
    *(s8v*)&Bl[2048 + t * 8] = g3;
    __syncthreads();
#pragma unroll
    for (int ct = 0; ct < 8; ++ct) {
      h8v bh = *(const h8v*)&Bh[ct * 512 + lane * 8];
      h8v bl = *(const h8v*)&Bl[ct * 512 + lane * 8];
      accH[ct] = __builtin_amdgcn_mfma_f32_16x16x32_f16(a0, bh, accH[ct], 0, 0, 0);
      accL[ct] = __builtin_amdgcn_mfma_f32_16x16x32_f16(a0, bl, accL[ct], 0, 0, 0);
    }
  }
  // epilogue: C/D layout col = lane&15, row = (lane>>4)*4 + reg
  int crow = (lane >> 4) * 4;
  int ccol = lane & 15;
  const float inv2048 = 1.0f / 2048.0f;
#pragma unroll
  for (int reg = 0; reg < 4; ++reg) {
    int gRow = rowBase + crow + reg;
    if (gRow >= N) continue;
#pragma unroll
    for (int ct = 0; ct < 8; ++ct) {
      int col = ct * 16 + ccol;
      float vv = accH[ct][reg] + accL[ct][reg] * inv2048 + bias[col];
      if (relu) vv = fmaxf(vv, 0.f);
      out[(size_t)gRow * NCH + col] = __float2half(vv);
    }
  }
}

// ---------------- pooling + final linear ----------------

__global__ __launch_bounds__(128) void pool_kernel(const __half* __restrict__ h,
                                                   const int* __restrict__ batch,
                                                   float* __restrict__ sums,
                                                   float* __restrict__ gcnt, int N) {
  int start = blockIdx.x * POOL_CHUNK;
  if (start >= N) return;
  int end = min(start + POOL_CHUNK, N);
  int c = threadIdx.x;
  float acc = 0.f;
  int cnt = 0;
  int cur = batch[start];
  for (int i = start; i < end; ++i) {
    int g = batch[i];
    if (g != cur) {
      atomicAdd(&sums[cur * NCH + c], acc);
      if (c == 0) atomicAdd(&gcnt[cur], (float)cnt);
      acc = 0.f; cnt = 0; cur = g;
    }
    acc += __half2float(h[(size_t)i * NCH + c]);
    ++cnt;
  }
  atomicAdd(&sums[cur * NCH + c], acc);
  if (c == 0) atomicAdd(&gcnt[cur], (float)cnt);
}

__global__ void final_kernel(const float* __restrict__ sums, const float* __restrict__ gcnt,
                             const float* __restrict__ lw, const float* __restrict__ lb,
                             float* __restrict__ out) {
  int g = blockIdx.x;
  int o = threadIdx.x;
  if (o >= OUTC) return;
  float inv = 1.0f / fmaxf(gcnt[g], 1.0f);
  float acc = lb[o];
  for (int ch = 0; ch < NCH; ++ch) acc += sums[g * NCH + ch] * inv * lw[ch * OUTC + o];
  out[g * OUTC + o] = acc;
}

// ---------------- launch ----------------

extern "C" void kernel_launch(void* const* d_in, const int* in_sizes, int n_in,
                              void* d_out, int out_size, void* d_ws, size_t ws_size,
                              hipStream_t stream) {
  const float* x  = (const float*)d_in[0];
  const int* ei   = (const int*)d_in[1];
  const int* batch= (const int*)d_in[2];
  const float* W0 = (const float*)d_in[3];
  const float* b0 = (const float*)d_in[4];
  const float* W1 = (const float*)d_in[5];
  const float* b1 = (const float*)d_in[6];
  const float* W2 = (const float*)d_in[7];
  const float* b2 = (const float*)d_in[8];
  const float* lw = (const float*)d_in[9];
  const float* lb = (const float*)d_in[10];
  float* out = (float*)d_out;
  int N = in_sizes[0] / NCH;
  int E = in_sizes[1] / 2;
  int RB = (N + NR - 1) / NR;  // bins per range (<= RBMAX)

  char* ws = (char*)d_ws;
  size_t off = 0;
  auto take = [&](size_t bytes) -> char* {
    char* p = ws + off;
    off += (bytes + 511) & ~(size_t)511;
    return p;
  };
  int* pc      = (int*)take((size_t)NBLK * NR * 4);
  int* pcS     = (int*)take((size_t)NBLK * NR * 4);
  int* pairOff = (int*)take((size_t)NBLK * NR * 4);
  int* srcOff  = (int*)take((size_t)NBLK * NR * 4);
  int* gbase   = (int*)take((NR + 1) * 4);
  int* sgbase  = (int*)take((NR + 1) * 4);
  int* dsts    = (int*)take((size_t)E * 4);
  int* srcs    = (int*)take((size_t)E * 4);
  int* srcpart = (int*)take((size_t)E * 4);
  int* pbinsD  = (int*)take((size_t)NR * BXS * RB * 4);
  int* pbinsS  = (int*)take((size_t)NR * BXS * RB * 4);
  int* sbase   = (int*)take((size_t)NR * BXS * RB * 4);
  float* dis   = (float*)take((size_t)N * 4);
  int* rp      = (int*)take((size_t)(N + 1) * 4);
  int2* sedge  = (int2*)take((size_t)E * 8);
  __half* x16  = (__half*)take((size_t)N * NCH * 2);
  __half* H16  = (__half*)take((size_t)N * NCH * 2);
  __half* P1h  = (__half*)take((size_t)N * NCH * 2);
  __half* P2h  = (__half*)take((size_t)N * NCH * 2);
  __half* WFhi = (__half*)take((size_t)3 * 3 * 128 * 128 * 2);
  __half* WFlo = (__half*)take((size_t)3 * 3 * 128 * 128 * 2);
  float* sums  = (float*)take((size_t)NGRAPHS * NCH * 4);
  float* gcnt  = (float*)take((size_t)NGRAPHS * 4);

  hipMemsetAsync(sums, 0, (size_t)NGRAPHS * NCH * 4, stream);
  hipMemsetAsync(gcnt, 0, (size_t)NGRAPHS * 4, stream);

  prep_w_kernel<<<(3 * 3 * 128 * 128 + 255) / 256, 256, 0, stream>>>(W0, W1, W2, WFhi, WFlo);
  f2h_kernel<<<(N * NCH / 4 + 255) / 256, 256, 0, stream>>>(x, x16, N * NCH);

  part_count_kernel<<<NBLK, 256, 0, stream>>>(ei, pc, pcS, E, RB);
  offs_kernel<<<1, 256, 0, stream>>>(pc, pcS, pairOff, srcOff, gbase, sgbase, E);
  partition_kernel<<<NBLK, 256, 0, stream>>>(ei, pairOff, srcOff, dsts, srcs, srcpart, E, RB);
  {
    dim3 g(BXS, NR, 1);
    binD_kernel<<<g, 256, 0, stream>>>(dsts, gbase, pbinsD, RB);
    binS_kernel<<<g, 256, 0, stream>>>(srcpart, sgbase, pbinsS, RB);
  }
  sc_dis_kernel<<<(N + 255) / 256, 256, 0, stream>>>(pbinsS, dis, N, RB);
  range_scan_kernel<<<NR, 256, 0, stream>>>(pbinsD, sbase, RB);
  rp_kernel<<<(N + 1 + 255) / 256, 256, 0, stream>>>(sbase, gbase, rp, N, RB, E);
  {
    dim3 g(BXS, NR, 1);
    place_kernel<<<g, 256, 0, stream>>>(dsts, srcs, dis, sbase, gbase, sedge, RB);
  }

  int pgrid = (N + 3) / 4;
  int ggrid = (N + 63) / 64;
  const int WL = 3 * 4 * 8 * 512;  // halfs per layer in WF layout

  // layer 0
  prop_kernel<<<pgrid, 256, 0, stream>>>(x16, P1h, rp, sedge, N);
  prop_kernel<<<pgrid, 256, 0, stream>>>(P1h, P2h, rp, sedge, N);
  gemm_cheb_mfma<<<ggrid, 256, 0, stream>>>(x16, P1h, P2h, WFhi + 0 * WL, WFlo + 0 * WL, b0, H16, N, 1);
  // layer 1 (out aliases h; safe: waves read only their own rows before writing them)
  prop_kernel<<<pgrid, 256, 0, stream>>>(H16, P1h, rp, sedge, N);
  prop_kernel<<<pgrid, 256, 0, stream>>>(P1h, P2h, rp, sedge, N);
  gemm_cheb_mfma<<<ggrid, 256, 0, stream>>>(H16, P1h, P2h, WFhi + 1 * WL, WFlo + 1 * WL, b1, H16, N, 1);
  // layer 2
  prop_kernel<<<pgrid, 256, 0, stream>>>(H16, P1h, rp, sedge, N);
  prop_kernel<<<pgrid, 256, 0, stream>>>(P1h, P2h, rp, sedge, N);
  gemm_cheb_mfma<<<ggrid, 256, 0, stream>>>(H16, P1h, P2h, WFhi + 2 * WL, WFlo + 2 * WL, b2, H16, N, 0);

  pool_kernel<<<(N + POOL_CHUNK - 1) / POOL_CHUNK, 128, 0, stream>>>(H16, batch, sums, gcnt, N);
  final_kernel<<<NGRAPHS, 16, 0, stream>>>(sums, gcnt, lw, lb, out);
}

// Round 13
// 658.618 us; speedup vs baseline: 1.5474x; 1.0947x over previous
//
#include <hip/hip_runtime.h>
#include <hip/hip_fp16.h>
#include <cstdint>

#define NCH 128
#define NGRAPHS 64
#define OUTC 10
#define POOL_CHUNK 128
#define NR 16      // dst/src ranges
#define BXS 32     // sub-blocks per range for bin/place
#define NBLK 512   // blocks for part/partition passes
#define RBMAX 6272 // max bins per range (N <= NR*RBMAX)

typedef __attribute__((ext_vector_type(8))) short s8v;
typedef __attribute__((ext_vector_type(8))) _Float16 h8v;
typedef __attribute__((ext_vector_type(4))) float f4v;

// ---------------- preprocessing: partition + counting sort, zero global atomics ----------------

__global__ __launch_bounds__(256) void part_count_kernel(const int* __restrict__ ei,
                                                         int* __restrict__ pc,
                                                         int* __restrict__ pcS,
                                                         int E, int RB) {
  __shared__ int cd[NR], cs[NR];
  int t = threadIdx.x, b = blockIdx.x;
  if (t < NR) { cd[t] = 0; cs[t] = 0; }
  __syncthreads();
  int chunk = (E + NBLK - 1) / NBLK;
  int i0 = b * chunk, i1 = min(i0 + chunk, E);
  for (int i = i0 + t; i < i1; i += 256) {
    atomicAdd(&cd[(unsigned)ei[E + i] / (unsigned)RB], 1);
    atomicAdd(&cs[(unsigned)ei[i] / (unsigned)RB], 1);
  }
  __syncthreads();
  if (t < NR) { pc[b * NR + t] = cd[t]; pcS[b * NR + t] = cs[t]; }
}

__global__ void offs_kernel(const int* __restrict__ pc, const int* __restrict__ pcS,
                            int* __restrict__ pairOff, int* __restrict__ srcOff,
                            int* __restrict__ gbase, int* __restrict__ sgbase, int E) {
  __shared__ int tot[NR], totS[NR];
  int t = threadIdx.x;
  if (t < NR) {
    int a = 0, as = 0;
    for (int b = 0; b < NBLK; ++b) { a += pc[b * NR + t]; as += pcS[b * NR + t]; }
    tot[t] = a; totS[t] = as;
  }
  __syncthreads();
  if (t == 0) {
    int acc = 0, accS = 0;
    for (int r = 0; r < NR; ++r) {
      gbase[r] = acc; acc += tot[r];
      sgbase[r] = accS; accS += totS[r];
    }
    gbase[NR] = E; sgbase[NR] = E;
  }
  __syncthreads();
  if (t < NR) {
    int acc = gbase[t], accS = sgbase[t];
    for (int b = 0; b < NBLK; ++b) {
      pairOff[b * NR + t] = acc; acc += pc[b * NR + t];
      srcOff[b * NR + t] = accS; accS += pcS[b * NR + t];
    }
  }
}

__global__ __launch_bounds__(256) void partition_kernel(const int* __restrict__ ei,
                                                        const int* __restrict__ pairOff,
                                                        const int* __restrict__ srcOff,
                                                        int* __restrict__ dsts,
                                                        int* __restrict__ srcs,
                                                        int* __restrict__ srcpart,
                                                        int E, int RB) {
  __shared__ int baseD[NR], baseS[NR], ctrD[NR], ctrS[NR];
  int t = threadIdx.x, b = blockIdx.x;
  if (t < NR) {
    baseD[t] = pairOff[b * NR + t]; ctrD[t] = 0;
    baseS[t] = srcOff[b * NR + t]; ctrS[t] = 0;
  }
  __syncthreads();
  int chunk = (E + NBLK - 1) / NBLK;
  int i0 = b * chunk, i1 = min(i0 + chunk, E);
  for (int i = i0 + t; i < i1; i += 256) {
    int d = ei[E + i], s = ei[i];
    int r = (unsigned)d / (unsigned)RB;
    int k = atomicAdd(&ctrD[r], 1);
    int pos = baseD[r] + k;
    dsts[pos] = d; srcs[pos] = s;
    int rs = (unsigned)s / (unsigned)RB;
    int k2 = atomicAdd(&ctrS[rs], 1);
    srcpart[baseS[rs] + k2] = s;
  }
}

__global__ __launch_bounds__(256) void binD_kernel(const int* __restrict__ dsts,
                                                   const int* __restrict__ gbase,
                                                   int* __restrict__ pbinsD, int RB) {
  __shared__ int bin[RBMAX];
  int t = threadIdx.x, x = blockIdx.x, y = blockIdx.y;
  for (int b = t; b < RB; b += 256) bin[b] = 0;
  __syncthreads();
  int segS = gbase[y], segE = gbase[y + 1];
  int chunk = (segE - segS + BXS - 1) / BXS;
  int i0 = segS + x * chunk, i1 = min(i0 + chunk, segE);
  int lo = y * RB;
  for (int i = i0 + t; i < i1; i += 256) atomicAdd(&bin[dsts[i] - lo], 1);
  __syncthreads();
  size_t base = (size_t)(y * BXS + x) * RB;
  for (int b = t; b < RB; b += 256) pbinsD[base + b] = bin[b];
}

__global__ __launch_bounds__(256) void binS_kernel(const int* __restrict__ srcpart,
                                                   const int* __restrict__ sgbase,
                                                   int* __restrict__ pbinsS, int RB) {
  __shared__ int bin[RBMAX];
  int t = threadIdx.x, x = blockIdx.x, y = blockIdx.y;
  for (int b = t; b < RB; b += 256) bin[b] = 0;
  __syncthreads();
  int segS = sgbase[y], segE = sgbase[y + 1];
  int chunk = (segE - segS + BXS - 1) / BXS;
  int i0 = segS + x * chunk, i1 = min(i0 + chunk, segE);
  int lo = y * RB;
  for (int i = i0 + t; i < i1; i += 256) atomicAdd(&bin[srcpart[i] - lo], 1);
  __syncthreads();
  size_t base = (size_t)(y * BXS + x) * RB;
  for (int b = t; b < RB; b += 256) pbinsS[base + b] = bin[b];
}

__global__ __launch_bounds__(256) void sc_dis_kernel(const int* __restrict__ pbinsS,
                                                     float* __restrict__ dis,
                                                     int N, int RB) {
  int n = blockIdx.x * 256 + threadIdx.x;
  if (n >= N) return;
  int y = n / RB, b = n - y * RB;
  int s = 0;
#pragma unroll
  for (int x = 0; x < BXS; ++x) s += pbinsS[(size_t)(y * BXS + x) * RB + b];
  dis[n] = s > 0 ? rsqrtf((float)s) : 0.0f;
}

__global__ __launch_bounds__(256) void range_scan_kernel(const int* __restrict__ pbinsD,
                                                         int* __restrict__ sbase, int RB) {
  __shared__ int wsum[4];
  __shared__ int carry_s;
  int t = threadIdx.x;
  int y = blockIdx.x;
  if (t == 0) carry_s = 0;
  __syncthreads();
  int nch = (RB + 255) / 256;
  for (int c = 0; c < nch; ++c) {
    int d = c * 256 + t;
    int v[BXS];
    int tv = 0;
#pragma unroll
    for (int x = 0; x < BXS; ++x) {
      v[x] = (d < RB) ? pbinsD[(size_t)(y * BXS + x) * RB + d] : 0;
      tv += v[x];
    }
    int lane = t & 63, w = t >> 6;
    int ps = tv;
    for (int dd = 1; dd < 64; dd <<= 1) {
      int o = __shfl_up(ps, dd);
      if (lane >= dd) ps += o;
    }
    if (lane == 63) wsum[w] = ps;
    __syncthreads();
    int woff = 0;
    for (int i = 0; i < w; ++i) woff += wsum[i];
    int ex = carry_s + woff + ps - tv;
    if (d < RB) {
      int run = ex;
#pragma unroll
      for (int x = 0; x < BXS; ++x) {
        sbase[(size_t)(y * BXS + x) * RB + d] = run;
        run += v[x];
      }
    }
    __syncthreads();
    if (t == 0) carry_s += wsum[0] + wsum[1] + wsum[2] + wsum[3];
    __syncthreads();
  }
}

__global__ __launch_bounds__(256) void rp_kernel(const int* __restrict__ sbase,
                                                 const int* __restrict__ gbase,
                                                 int* __restrict__ rp, int N, int RB, int E) {
  int n = blockIdx.x * 256 + threadIdx.x;
  if (n < N) {
    int y = n / RB, b = n - y * RB;
    rp[n] = gbase[y] + sbase[(size_t)(y * BXS) * RB + b];
  } else if (n == N) {
    rp[N] = E;
  }
}

__global__ __launch_bounds__(256) void place_kernel(const int* __restrict__ dsts,
                                                    const int* __restrict__ srcs,
                                                    const float* __restrict__ dis,
                                                    const int* __restrict__ sbase,
                                                    const int* __restrict__ gbase,
                                                    int2* __restrict__ sedge, int RB) {
  __shared__ int sb[RBMAX];
  int t = threadIdx.x, x = blockIdx.x, y = blockIdx.y;
  size_t pb = (size_t)(y * BXS + x) * RB;
  for (int b = t; b < RB; b += 256) sb[b] = sbase[pb + b];
  __syncthreads();
  int segS = gbase[y], segE = gbase[y + 1];
  int chunk = (segE - segS + BXS - 1) / BXS;
  int i0 = segS + x * chunk, i1 = min(i0 + chunk, segE);
  int lo = y * RB;
  int gb = gbase[y];
  for (int i = i0 + t; i < i1; i += 256) {
    int d = dsts[i], s = srcs[i];
    int pos = gb + atomicAdd(&sb[d - lo], 1);
    sedge[pos] = make_int2(s, __float_as_int(-dis[s] * dis[d]));
  }
}

__global__ __launch_bounds__(256) void f2h_kernel(const float* __restrict__ in,
                                                  __half* __restrict__ out, int n) {
  int i = (blockIdx.x * 256 + threadIdx.x) * 4;
  if (i + 3 < n) {
    float4 v = *(const float4*)&in[i];
    __half2 a = __float22half2_rn(make_float2(v.x, v.y));
    __half2 b = __float22half2_rn(make_float2(v.z, v.w));
    *(__half2*)&out[i] = a;
    *(__half2*)&out[i + 2] = b;
  } else {
    for (; i < n; ++i) out[i] = __float2half(in[i]);
  }
}

// --- weight prep: PRECOMBINED phases (W0-W2, W1, 2*W2) + fp16 hi/lo(x2^11) split ---
__global__ __launch_bounds__(256) void prep_w_kernel(const float* __restrict__ W0,
                                                     const float* __restrict__ W1,
                                                     const float* __restrict__ W2,
                                                     __half* __restrict__ WFhi,
                                                     __half* __restrict__ WFlo) {
  int idx = blockIdx.x * 256 + threadIdx.x;
  const int TOT = 3 * 3 * 128 * 128;
  if (idx >= TOT) return;
  int j = idx & 7;
  int lane = (idx >> 3) & 63;
  int ct = (idx >> 9) & 7;
  int kwin = (idx >> 12) & 3;
  int p = (idx >> 14) % 3;
  int L = idx / (3 * 16384);
  int k = kwin * 32 + (lane >> 4) * 8 + j;
  int col = ct * 16 + (lane & 15);
  const float* W = (L == 0) ? W0 : ((L == 1) ? W1 : W2);
  float v;
  if (p == 0)      v = W[(0 * 128 + k) * 128 + col] - W[(2 * 128 + k) * 128 + col];
  else if (p == 1) v = W[(1 * 128 + k) * 128 + col];
  else             v = 2.0f * W[(2 * 128 + k) * 128 + col];
  __half hi = __float2half_rn(v);
  float resid = v - __half2float(hi);
  __half lo = __float2half_rn(resid * 2048.0f);
  WFhi[idx] = hi;
  WFlo[idx] = lo;
}

// ---------------- propagate (fp16): out[i] = sum_e norm_e * h[src_e] ----------------
// 16 lanes per edge (16B/lane); 16 edges per iteration = 4 row-loads in flight per lane.
__device__ __forceinline__ void fma8(float* a, float w, uint4 raw) {
  __half2* ph = (__half2*)&raw;
#pragma unroll
  for (int j = 0; j < 4; ++j) {
    float2 f = __half22float2(ph[j]);
    a[2 * j] += w * f.x;
    a[2 * j + 1] += w * f.y;
  }
}

__global__ __launch_bounds__(256) void prop_kernel(const __half* __restrict__ h,
                                                   __half* __restrict__ out,
                                                   const int* __restrict__ rp,
                                                   const int2* __restrict__ sedge, int N) {
  int node = blockIdx.x * 4 + (threadIdx.x >> 6);
  if (node >= N) return;
  int lane = threadIdx.x & 63;
  int q = lane >> 4;           // quarter owns edge e+q
  int c = (lane & 15) * 8;     // 8 halves = 16B per lane
  int e0 = rp[node], e1 = rp[node + 1];
  float a[8];
#pragma unroll
  for (int j = 0; j < 8; ++j) a[j] = 0.f;
  int e = e0;
  for (; e + 16 <= e1; e += 16) {  // 16 edges in flight (4 loads/lane)
    int2 E0 = sedge[e + q];
    int2 E1 = sedge[e + 4 + q];
    int2 E2 = sedge[e + 8 + q];
    int2 E3 = sedge[e + 12 + q];
    uint4 r0 = *(const uint4*)&h[(size_t)E0.x * NCH + c];
    uint4 r1 = *(const uint4*)&h[(size_t)E1.x * NCH + c];
    uint4 r2 = *(const uint4*)&h[(size_t)E2.x * NCH + c];
    uint4 r3 = *(const uint4*)&h[(size_t)E3.x * NCH + c];
    fma8(a, __int_as_float(E0.y), r0);
    fma8(a, __int_as_float(E1.y), r1);
    fma8(a, __int_as_float(E2.y), r2);
    fma8(a, __int_as_float(E3.y), r3);
  }
  for (; e + 4 <= e1; e += 4) {
    int2 E0 = sedge[e + q];
    uint4 r0 = *(const uint4*)&h[(size_t)E0.x * NCH + c];
    fma8(a, __int_as_float(E0.y), r0);
  }
  if (e < e1) {
    int idx = e + q;
    if (idx < e1) {
      int2 E0 = sedge[idx];
      uint4 r0 = *(const uint4*)&h[(size_t)E0.x * NCH + c];
      fma8(a, __int_as_float(E0.y), r0);
    }
  }
#pragma unroll
  for (int j = 0; j < 8; ++j) {
    a[j] += __shfl_xor(a[j], 16);
    a[j] += __shfl_xor(a[j], 32);
  }
  if (q == 0) {
    uint4 st;
    __half2* ph = (__half2*)&st;
#pragma unroll
    for (int j = 0; j < 4; ++j)
      ph[j] = __float22half2_rn(make_float2(a[2 * j], a[2 * j + 1]));
    *(uint4*)&out[(size_t)node * NCH + c] = st;
  }
}

// ------- fused Cheb GEMM v3: B staged through LDS, A global->reg, precombined W -------
__global__ __launch_bounds__(256) void gemm_cheb_mfma(
    const __half* h, const __half* p1, const __half* p2,
    const __half* __restrict__ WFhi, const __half* __restrict__ WFlo,
    const float* __restrict__ bias, __half* out, int N, int relu) {
  __shared__ __align__(16) __half Bh[4096];
  __shared__ __align__(16) __half Bl[4096];
  int t = threadIdx.x;
  int w = t >> 6, lane = t & 63;
  int rowBase = blockIdx.x * 64 + w * 16;
  int r0 = min(rowBase + (lane & 15), N - 1);  // clamped; OOB rows never stored
  int kb = (lane >> 4) * 8;

  f4v accH[8], accL[8];
#pragma unroll
  for (int ct = 0; ct < 8; ++ct) { accH[ct] = (f4v)0.f; accL[ct] = (f4v)0.f; }

  for (int s = 0; s < 12; ++s) {
    int phase = s >> 2, kwin = s & 3;
    const __half* bsrcH = WFhi + s * 4096;
    const __half* bsrcL = WFlo + s * 4096;
    s8v g0 = *(const s8v*)&bsrcH[t * 8];
    s8v g1 = *(const s8v*)&bsrcH[2048 + t * 8];
    s8v g2 = *(const s8v*)&bsrcL[t * 8];
    s8v g3 = *(const s8v*)&bsrcL[2048 + t * 8];
    int k = kwin * 32 + kb;
    h8v a0;
    if (phase == 0)      a0 = *(const h8v*)&h [(size_t)r0 * NCH + k];
    else if (phase == 1) a0 = *(const h8v*)&p1[(size_t)r0 * NCH + k];
    else                 a0 = *(const h8v*)&p2[(size_t)r0 * NCH + k];
    if (s) __syncthreads();
    *(s8v*)&Bh[t * 8] = g0;
    *(s8v*)&Bh[2048 + t * 8] = g1;
    *(s8v*)&Bl[t * 8] = g2;
    *(s8v*)&Bl[2048 + t * 8] = g3;
    __syncthreads();
#pragma unroll
    for (int ct = 0; ct < 8; ++ct) {
      h8v bh = *(const h8v*)&Bh[ct * 512 + lane * 8];
      h8v bl = *(const h8v*)&Bl[ct * 512 + lane * 8];
      accH[ct] = __builtin_amdgcn_mfma_f32_16x16x32_f16(a0, bh, accH[ct], 0, 0, 0);
      accL[ct] = __builtin_amdgcn_mfma_f32_16x16x32_f16(a0, bl, accL[ct], 0, 0, 0);
    }
  }
  int crow = (lane >> 4) * 4;
  int ccol = lane & 15;
  const float inv2048 = 1.0f / 2048.0f;
#pragma unroll
  for (int reg = 0; reg < 4; ++reg) {
    int gRow = rowBase + crow + reg;
    if (gRow >= N) continue;
#pragma unroll
    for (int ct = 0; ct < 8; ++ct) {
      int col = ct * 16 + ccol;
      float vv = accH[ct][reg] + accL[ct][reg] * inv2048 + bias[col];
      if (relu) vv = fmaxf(vv, 0.f);
      out[(size_t)gRow * NCH + col] = __float2half(vv);
    }
  }
}

// ---------------- pooling + final linear ----------------
// v2: 8-row software pipeline (8 independent loads in flight), 128-row chunks.
__global__ __launch_bounds__(128) void pool_kernel(const __half* __restrict__ h,
                                                   const int* __restrict__ batch,
                                                   float* __restrict__ sums,
                                                   float* __restrict__ gcnt, int N) {
  int start = blockIdx.x * POOL_CHUNK;
  if (start >= N) return;
  int end = min(start + POOL_CHUNK, N);
  int c = threadIdx.x;
  float acc = 0.f;
  int cnt = 0;
  int cur = batch[start];
  int i = start;
  for (; i + 8 <= end; i += 8) {
    __half v0 = h[(size_t)(i + 0) * NCH + c];
    __half v1 = h[(size_t)(i + 1) * NCH + c];
    __half v2 = h[(size_t)(i + 2) * NCH + c];
    __half v3 = h[(size_t)(i + 3) * NCH + c];
    __half v4 = h[(size_t)(i + 4) * NCH + c];
    __half v5 = h[(size_t)(i + 5) * NCH + c];
    __half v6 = h[(size_t)(i + 6) * NCH + c];
    __half v7 = h[(size_t)(i + 7) * NCH + c];
    int b7 = batch[i + 7];
    if (b7 == cur) {  // fast path: whole group same graph (boundaries are rare)
      float s01 = __half2float(v0) + __half2float(v1);
      float s23 = __half2float(v2) + __half2float(v3);
      float s45 = __half2float(v4) + __half2float(v5);
      float s67 = __half2float(v6) + __half2float(v7);
      acc += (s01 + s23) + (s45 + s67);
      cnt += 8;
    } else {
      __half vv[8] = {v0, v1, v2, v3, v4, v5, v6, v7};
#pragma unroll
      for (int j = 0; j < 8; ++j) {
        int b = batch[i + j];
        if (b != cur) {
          atomicAdd(&sums[cur * NCH + c], acc);
          if (c == 0) atomicAdd(&gcnt[cur], (float)cnt);
          acc = 0.f; cnt = 0; cur = b;
        }
        acc += __half2float(vv[j]);
        ++cnt;
      }
    }
  }
  for (; i < end; ++i) {
    int b = batch[i];
    if (b != cur) {
      atomicAdd(&sums[cur * NCH + c], acc);
      if (c == 0) atomicAdd(&gcnt[cur], (float)cnt);
      acc = 0.f; cnt = 0; cur = b;
    }
    acc += __half2float(h[(size_t)i * NCH + c]);
    ++cnt;
  }
  atomicAdd(&sums[cur * NCH + c], acc);
  if (c == 0) atomicAdd(&gcnt[cur], (float)cnt);
}

__global__ void final_kernel(const float* __restrict__ sums, const float* __restrict__ gcnt,
                             const float* __restrict__ lw, const float* __restrict__ lb,
                             float* __restrict__ out) {
  int g = blockIdx.x;
  int o = threadIdx.x;
  if (o >= OUTC) return;
  float inv = 1.0f / fmaxf(gcnt[g], 1.0f);
  float acc = lb[o];
  for (int ch = 0; ch < NCH; ++ch) acc += sums[g * NCH + ch] * inv * lw[ch * OUTC + o];
  out[g * OUTC + o] = acc;
}

// ---------------- launch ----------------

extern "C" void kernel_launch(void* const* d_in, const int* in_sizes, int n_in,
                              void* d_out, int out_size, void* d_ws, size_t ws_size,
                              hipStream_t stream) {
  const float* x  = (const float*)d_in[0];
  const int* ei   = (const int*)d_in[1];
  const int* batch= (const int*)d_in[2];
  const float* W0 = (const float*)d_in[3];
  const float* b0 = (const float*)d_in[4];
  const float* W1 = (const float*)d_in[5];
  const float* b1 = (const float*)d_in[6];
  const float* W2 = (const float*)d_in[7];
  const float* b2 = (const float*)d_in[8];
  const float* lw = (const float*)d_in[9];
  const float* lb = (const float*)d_in[10];
  float* out = (float*)d_out;
  int N = in_sizes[0] / NCH;
  int E = in_sizes[1] / 2;
  int RB = (N + NR - 1) / NR;  // bins per range (<= RBMAX)

  char* ws = (char*)d_ws;
  size_t off = 0;
  auto take = [&](size_t bytes) -> char* {
    char* p = ws + off;
    off += (bytes + 511) & ~(size_t)511;
    return p;
  };
  int* pc      = (int*)take((size_t)NBLK * NR * 4);
  int* pcS     = (int*)take((size_t)NBLK * NR * 4);
  int* pairOff = (int*)take((size_t)NBLK * NR * 4);
  int* srcOff  = (int*)take((size_t)NBLK * NR * 4);
  int* gbase   = (int*)take((NR + 1) * 4);
  int* sgbase  = (int*)take((NR + 1) * 4);
  int* dsts    = (int*)take((size_t)E * 4);
  int* srcs    = (int*)take((size_t)E * 4);
  int* srcpart = (int*)take((size_t)E * 4);
  int* pbinsD  = (int*)take((size_t)NR * BXS * RB * 4);
  int* pbinsS  = (int*)take((size_t)NR * BXS * RB * 4);
  int* sbase   = (int*)take((size_t)NR * BXS * RB * 4);
  float* dis   = (float*)take((size_t)N * 4);
  int* rp      = (int*)take((size_t)(N + 1) * 4);
  int2* sedge  = (int2*)take((size_t)E * 8);
  __half* x16  = (__half*)take((size_t)N * NCH * 2);
  __half* H16  = (__half*)take((size_t)N * NCH * 2);
  __half* P1h  = (__half*)take((size_t)N * NCH * 2);
  __half* P2h  = (__half*)take((size_t)N * NCH * 2);
  __half* WFhi = (__half*)take((size_t)3 * 3 * 128 * 128 * 2);
  __half* WFlo = (__half*)take((size_t)3 * 3 * 128 * 128 * 2);
  float* sums  = (float*)take((size_t)NGRAPHS * NCH * 4);
  float* gcnt  = (float*)take((size_t)NGRAPHS * 4);

  hipMemsetAsync(sums, 0, (size_t)NGRAPHS * NCH * 4, stream);
  hipMemsetAsync(gcnt, 0, (size_t)NGRAPHS * 4, stream);

  prep_w_kernel<<<(3 * 3 * 128 * 128 + 255) / 256, 256, 0, stream>>>(W0, W1, W2, WFhi, WFlo);
  f2h_kernel<<<(N * NCH / 4 + 255) / 256, 256, 0, stream>>>(x, x16, N * NCH);

  part_count_kernel<<<NBLK, 256, 0, stream>>>(ei, pc, pcS, E, RB);
  offs_kernel<<<1, 256, 0, stream>>>(pc, pcS, pairOff, srcOff, gbase, sgbase, E);
  partition_kernel<<<NBLK, 256, 0, stream>>>(ei, pairOff, srcOff, dsts, srcs, srcpart, E, RB);
  {
    dim3 g(BXS, NR, 1);
    binD_kernel<<<g, 256, 0, stream>>>(dsts, gbase, pbinsD, RB);
    binS_kernel<<<g, 256, 0, stream>>>(srcpart, sgbase, pbinsS, RB);
  }
  sc_dis_kernel<<<(N + 255) / 256, 256, 0, stream>>>(pbinsS, dis, N, RB);
  range_scan_kernel<<<NR, 256, 0, stream>>>(pbinsD, sbase, RB);
  rp_kernel<<<(N + 1 + 255) / 256, 256, 0, stream>>>(sbase, gbase, rp, N, RB, E);
  {
    dim3 g(BXS, NR, 1);
    place_kernel<<<g, 256, 0, stream>>>(dsts, srcs, dis, sbase, gbase, sedge, RB);
  }

  int pgrid = (N + 3) / 4;
  int ggrid = (N + 63) / 64;
  const int WL = 3 * 4 * 8 * 512;  // halfs per layer in WF layout

  // layer 0
  prop_kernel<<<pgrid, 256, 0, stream>>>(x16, P1h, rp, sedge, N);
  prop_kernel<<<pgrid, 256, 0, stream>>>(P1h, P2h, rp, sedge, N);
  gemm_cheb_mfma<<<ggrid, 256, 0, stream>>>(x16, P1h, P2h, WFhi + 0 * WL, WFlo + 0 * WL, b0, H16, N, 1);
  // layer 1 (out aliases h; safe: waves read only their own rows before writing them)
  prop_kernel<<<pgrid, 256, 0, stream>>>(H16, P1h, rp, sedge, N);
  prop_kernel<<<pgrid, 256, 0, stream>>>(P1h, P2h, rp, sedge, N);
  gemm_cheb_mfma<<<ggrid, 256, 0, stream>>>(H16, P1h, P2h, WFhi + 1 * WL, WFlo + 1 * WL, b1, H16, N, 1);
  // layer 2
  prop_kernel<<<pgrid, 256, 0, stream>>>(H16, P1h, rp, sedge, N);
  prop_kernel<<<pgrid, 256, 0, stream>>>(P1h, P2h, rp, sedge, N);
  gemm_cheb_mfma<<<ggrid, 256, 0, stream>>>(H16, P1h, P2h, WFhi + 2 * WL, WFlo + 2 * WL, b2, H16, N, 0);

  pool_kernel<<<(N + POOL_CHUNK - 1) / POOL_CHUNK, 128, 0, stream>>>(H16, batch, sums, gcnt, N);
  final_kernel<<<NGRAPHS, 16, 0, stream>>>(sums, gcnt, lw, lb, out);
}